// Round 5
// baseline (962.121 us; speedup 1.0000x reference)
//
#include <hip/hip_runtime.h>

// LocalAttention (Swin scrambled-window variant) — all four GEMMs on MFMA.
// Window map (verified pass R2/R3): n=b*1024+c*16+t ; c2=hi*32+lo ; p=r*8+s ;
// h=16t+8hi+r ; w=8lo+s ; mask index = n&1023.
// l2norm folds into k:  attn[i][j] = sum_c q[c][i] * (k[c][j]*0.125/(nq_c*nk_c)).
// Split-bf16 everywhere: x=hi+lo, D += Ah*Bh + Ah*Bl + Al*Bh (rel err ~2^-18).
//
// R8: 5 blocks/CU via LDS 40960 -> 32768 exactly (5*32768 = 163840 = full LDS).
//   - kT split by channel-halves: K0 (c<32) 8KB + K1 (c>=32) 8KB, stride-32,
//     kswz key ((r>>3)^(r>>1))&3 (enumerated: fragment reads at 8-lane/slot floor).
//     P5's kk=0/1 selects region at compile time.
//   - Front reordered q0,q1,v0,v1,k0,k1; scr (8KB fp32) overlays K1, which is
//     written only by dk1's scatter AFTER scr's last read. Front peak = 32KB.
//   - P6 as two K(=i)-halves: vb-half (8KB) + PT-half (8KB) rebuilt per half,
//     acc in regs across halves. Back-end peak = 32KB.
//   - P7 zero span at smem+16384: XTh magic row 128 / XTl magic row 64 (xkey=0);
//     zeroed post-P6; projo stores barrier-gated after the tap loop (span overlap).
//   Arena: R1[0,16384) XTin->qT->XTout ; R2[16384,32768) K0|K1(scr) -> vb|PT
//          halves -> zero-span+projo.
//   22 barriers; __launch_bounds__(256,5).

typedef __attribute__((ext_vector_type(8))) short bf8;
typedef __attribute__((ext_vector_type(4))) float f32x4;
#define MFMA(a, b, c) __builtin_amdgcn_mfma_f32_16x16x32_bf16(a, b, c, 0, 0, 0)

__device__ __forceinline__ int xkey(int p) { return ((p >> 3) ^ p) & 7; }
// bf16 64-wide regions: row p, col c (0..63) -> short index
__device__ __forceinline__ int xswz(int p, int c) { return p * 64 + (c ^ (xkey(p) << 3)); }
// bf16 32-wide regions (kT halves, vb/PT halves): row r, col c (0..31)
__device__ __forceinline__ int kswz(int r, int c) {
    return r * 32 + (c ^ ((((r >> 3) ^ (r >> 1)) & 3) << 3));
}
// scr fp32 (32 ch): stride 64, granule-4 XOR (uniform for P2 store + dw stencil)
__device__ __forceinline__ int sswz(int ch, int p) {
    return ch * 64 + (p ^ (((ch >> 1) & 7) << 2));
}
// projo fp32 (64 ch): stride 64, granule-8 XOR (uniform store, 2-way P8 read)
__device__ __forceinline__ int jswz(int ch, int p) {
    return ch * 64 + (p ^ (((ch >> 1) & 7) << 3));
}

// packed 2xf32 -> 2xbf16 (RNE). No builtin on gfx950 — inline asm (T12/m240).
__device__ __forceinline__ unsigned cvtpk(float a, float b) {
    unsigned r;
    asm("v_cvt_pk_bf16_f32 %0, %1, %2" : "=v"(r) : "v"(a), "v"(b));
    return r;
}

__device__ __forceinline__ void bsplit(float f, short& h, short& l) {
    unsigned u = __float_as_uint(f);
    unsigned hb = (u + 0x7FFFu + ((u >> 16) & 1u)) >> 16;
    float hf = __uint_as_float(hb << 16);
    float r = f - hf;
    unsigned u2 = __float_as_uint(r);
    unsigned lb = (u2 + 0x7FFFu + ((u2 >> 16) & 1u)) >> 16;
    h = (short)hb; l = (short)lb;
}
// a in low half, b in high half. hi = RNE-bf16(x); lo = RNE-bf16(x - hi).
__device__ __forceinline__ void bsplit2(float a, float b, unsigned& hw, unsigned& lw) {
    hw = cvtpk(a, b);
    float ra = a - __uint_as_float(hw << 16);
    float rb = b - __uint_as_float(hw & 0xFFFF0000u);
    lw = cvtpk(ra, rb);
}

// ---- qkv 1x1 weight fragments: [kk(2)][tt(12)][lane(64)][j(8)]  B[n=oc][k=ic] ----
__global__ void k_fq(const float* __restrict__ wq, short* __restrict__ oh, short* __restrict__ ol) {
    int bx = blockIdx.x;                 // kk*12 + tt
    int kk = bx / 12, tt = bx % 12;
    int tid = threadIdx.x;               // 512
    int lane = tid >> 3, j = tid & 7;
    int oc = tt * 16 + (lane & 15);
    int ic = kk * 32 + ((lane >> 4) << 3) + j;
    short h, l; bsplit(wq[oc * 64 + ic], h, l);
    oh[bx * 512 + tid] = h; ol[bx * 512 + tid] = l;
}
// ---- proj 3x3 weight fragments: [tap(9)][kk(2)][tt(4)][lane(64)][j(8)] ----
__global__ void k_fp(const float* __restrict__ wp, short* __restrict__ oh, short* __restrict__ ol) {
    int bx = blockIdx.x;                 // tap*8 + kk*4 + tt
    int tap = bx >> 3, kk = (bx >> 2) & 1, tt = bx & 3;
    int tid = threadIdx.x;
    int lane = tid >> 3, j = tid & 7;
    int oc = tt * 16 + (lane & 15);
    int ic = kk * 32 + ((lane >> 4) << 3) + j;
    short h, l; bsplit(wp[(oc * 64 + ic) * 9 + tap], h, l);
    oh[bx * 512 + tid] = h; ol[bx * 512 + tid] = l;
}

// dw3x3 for ONE channel (local ch 0..31 in scr), one output row, zero pad.
__device__ __forceinline__ void dw_one(const float* scr, const float* wd,
                                       int ch, int row, float o[8]) {
    float w9[9];
    #pragma unroll
    for (int tp = 0; tp < 9; ++tp) w9[tp] = wd[tp];
    float e[3][10];
    #pragma unroll
    for (int k3 = 0; k3 < 3; ++k3) {
        int rr = row - 1 + k3;
        e[k3][0] = 0.f; e[k3][9] = 0.f;
        if ((unsigned)rr < 8u) {
            float4 a = *(const float4*)&scr[sswz(ch, rr * 8)];
            float4 b = *(const float4*)&scr[sswz(ch, rr * 8 + 4)];
            e[k3][1] = a.x; e[k3][2] = a.y; e[k3][3] = a.z; e[k3][4] = a.w;
            e[k3][5] = b.x; e[k3][6] = b.y; e[k3][7] = b.z; e[k3][8] = b.w;
        } else {
            #pragma unroll
            for (int q2 = 1; q2 < 9; ++q2) e[k3][q2] = 0.f;
        }
    }
    #pragma unroll
    for (int s = 0; s < 8; ++s) {
        float a = 0.f;
        #pragma unroll
        for (int k3 = 0; k3 < 3; ++k3)
            #pragma unroll
            for (int dx = 0; dx < 3; ++dx)
                a = fmaf(w9[k3 * 3 + dx], e[k3][s + dx], a);
        o[s] = a;
    }
}

__device__ __forceinline__ float norm8(const float d[8]) {
    float ss = 0.f;
    #pragma unroll
    for (int s = 0; s < 8; ++s) ss = fmaf(d[s], d[s], ss);
    ss += __shfl_xor(ss, 1); ss += __shfl_xor(ss, 2); ss += __shfl_xor(ss, 4);
    return fmaxf(sqrtf(ss), 1e-12f);
}

// P2 chunk: 64px x 32oc x 64ic MFMA 1x1, XTin -> scr.
// chunk selects oc-16-tile pair: 0,1=q ; 2,3=k ; 4,5=v (tt = chunk*2+nh).
__device__ __forceinline__ void p2_chunk32(const short* XTh, const short* XTl,
                                           const short* bqh, const short* bql,
                                           float* scr, int chunk,
                                           int mh, int nh, int col, int quad, int qo8, int lane)
{
    f32x4 acc[2];
    #pragma unroll
    for (int mt = 0; mt < 2; ++mt) acc[mt] = (f32x4){0.f, 0.f, 0.f, 0.f};
    #pragma unroll
    for (int kk = 0; kk < 2; ++kk) {
        bf8 Ah[2], Al[2];
        #pragma unroll
        for (int mt = 0; mt < 2; ++mt) {
            int row = (mh * 2 + mt) * 16 + col;
            int ad = row * 64 + ((kk * 32 + qo8) ^ (xkey(row) << 3));
            Ah[mt] = *(const bf8*)&XTh[ad];
            Al[mt] = *(const bf8*)&XTl[ad];
        }
        int tt = chunk * 2 + nh;
        bf8 Bh = *(const bf8*)&bqh[((kk * 12 + tt) * 64 + lane) * 8];
        bf8 Bl = *(const bf8*)&bql[((kk * 12 + tt) * 64 + lane) * 8];
        #pragma unroll
        for (int mt = 0; mt < 2; ++mt) {
            acc[mt] = MFMA(Ah[mt], Bh, acc[mt]);
            acc[mt] = MFMA(Ah[mt], Bl, acc[mt]);
            acc[mt] = MFMA(Al[mt], Bh, acc[mt]);
        }
    }
    #pragma unroll
    for (int mt = 0; mt < 2; ++mt) {
        int ocl = nh * 16 + col;
        int p0 = (mh * 2 + mt) * 16 + quad * 4;
        *(f32x4*)&scr[sswz(ocl, p0)] = acc[mt];
    }
}

__global__ __launch_bounds__(256, 5)
void k_fused(const float* __restrict__ in,
             const short* __restrict__ bqh, const short* __restrict__ bql,
             const float* __restrict__ wdw,
             const short* __restrict__ bph, const short* __restrict__ bpl,
             float* __restrict__ out, int shift, int use_mask, int roll)
{
    __shared__ __align__(16) char smem[32768];
    short* XTh = (short*)smem;                 // R1: XTin -> qT -> XTout (8KB)
    short* XTl = (short*)(smem + 8192);        //     (8KB)
    short* K0h = (short*)(smem + 16384);       // kT c<32 hi (4KB)
    short* K0l = (short*)(smem + 20480);       // kT c<32 lo (4KB)
    short* K1h = (short*)(smem + 24576);       // kT c>=32 hi (4KB)
    short* K1l = (short*)(smem + 28672);       // kT c>=32 lo (4KB)
    float* scr = (float*)(smem + 24576);       // overlays K1 during front (8KB)
    short* vbh = (short*)(smem + 16384);       // P6: vb half hi (4KB)
    short* vbl = (short*)(smem + 20480);       //     vb half lo (4KB)
    short* PTf = (short*)(smem + 24576);       //     PT half hi (4KB)
    short* PTg = (short*)(smem + 28672);       //     PT half lo (4KB)
    float* projo = (float*)(smem + 16384);     // after P7 (16KB; zero span at +0)

    const int tid = threadIdx.x, lane = tid & 63, wv = tid >> 6;
    const int col = lane & 15, quad = lane >> 4, qo8 = quad * 8;
    const int mh = wv & 1, nh = wv >> 1;
    const int ch = tid >> 3, rrow = tid & 7;   // DW map: 1 channel/thread
    const int n = blockIdx.x;
    const int b = n >> 10, c = (n >> 4) & 63, t = n & 15;
    const size_t base = ((size_t)(b * 64 + c)) << 16;

    // ---- P1: load window (shift folded), split via cvt_pk pairs, XTin[p][c2] ----
    #pragma unroll
    for (int k = 0; k < 16; k += 2) {
        int o0 = tid + k * 256, o1 = o0 + 256;
        int hi0 = o0 >> 11, r0 = (o0 >> 8) & 7, lo0 = (o0 >> 3) & 31, s0 = o0 & 7;
        int hi1 = o1 >> 11, r1 = (o1 >> 8) & 7, lo1 = (o1 >> 3) & 31, s1 = o1 & 7;
        float v0 = in[base + (size_t)(((t * 16 + hi0 * 8 + r0) + shift) & 255) * 256
                           + (((lo0 * 8 + s0) + shift) & 255)];
        float v1 = in[base + (size_t)(((t * 16 + hi1 * 8 + r1) + shift) & 255) * 256
                           + (((lo1 * 8 + s1) + shift) & 255)];
        unsigned hw, lw; bsplit2(v0, v1, hw, lw);
        int ad0 = xswz(r0 * 8 + s0, hi0 * 32 + lo0);
        int ad1 = xswz(r1 * 8 + s1, hi1 * 32 + lo1);
        XTh[ad0] = (short)hw; XTh[ad1] = (short)(hw >> 16);
        XTl[ad0] = (short)lw; XTl[ad1] = (short)(lw >> 16);
    }
    __syncthreads();   // (1)

    float dqA[8], dqB[8], dvA[8], dvB[8];
    float nqA, nqB;

    // ---- q0 (oc tiles 0,1) ----
    p2_chunk32(XTh, XTl, bqh, bql, scr, 0, mh, nh, col, quad, qo8, lane);
    __syncthreads();   // (2)
    dw_one(scr, wdw + ch * 9, ch, rrow, dqA);
    nqA = norm8(dqA);
    __syncthreads();   // (3)
    // ---- q1 (oc tiles 2,3) ----
    p2_chunk32(XTh, XTl, bqh, bql, scr, 1, mh, nh, col, quad, qo8, lane);
    __syncthreads();   // (4)
    dw_one(scr, wdw + (32 + ch) * 9, ch, rrow, dqB);
    nqB = norm8(dqB);
    __syncthreads();   // (5)
    // ---- v0 (oc tiles 8,9) ----
    p2_chunk32(XTh, XTl, bqh, bql, scr, 4, mh, nh, col, quad, qo8, lane);
    __syncthreads();   // (6)
    dw_one(scr, wdw + (128 + ch) * 9, ch, rrow, dvA);
    __syncthreads();   // (7)
    // ---- v1 (oc tiles 10,11) ----
    p2_chunk32(XTh, XTl, bqh, bql, scr, 5, mh, nh, col, quad, qo8, lane);
    __syncthreads();   // (8)
    dw_one(scr, wdw + (160 + ch) * 9, ch, rrow, dvB);
    __syncthreads();   // (9)
    // ---- k0 (oc tiles 4,5): dk -> regs, scatter -> K0 (disjoint from scr=K1) ----
    p2_chunk32(XTh, XTl, bqh, bql, scr, 2, mh, nh, col, quad, qo8, lane);
    __syncthreads();   // (10)
    {
        float dk[8];
        dw_one(scr, wdw + (64 + ch) * 9, ch, rrow, dk);
        float sc = 0.125f / (nqA * norm8(dk));
        #pragma unroll
        for (int s = 0; s < 8; ++s) dk[s] *= sc;
        #pragma unroll
        for (int s0 = 0; s0 < 8; s0 += 2) {
            unsigned hw, lw; bsplit2(dk[s0], dk[s0 + 1], hw, lw);
            int p0 = rrow * 8 + s0;
            int a0 = kswz(p0, ch), a1 = kswz(p0 + 1, ch);
            K0h[a0] = (short)hw; K0h[a1] = (short)(hw >> 16);
            K0l[a0] = (short)lw; K0l[a1] = (short)(lw >> 16);
        }
    }
    __syncthreads();   // (11)
    // ---- k1 (oc tiles 6,7): last XTin reader ----
    p2_chunk32(XTh, XTl, bqh, bql, scr, 3, mh, nh, col, quad, qo8, lane);
    __syncthreads();   // (12)
    float dk1[8];
    dw_one(scr, wdw + (96 + ch) * 9, ch, rrow, dk1);
    {
        float sc = 0.125f / (nqB * norm8(dk1));
        #pragma unroll
        for (int s = 0; s < 8; ++s) dk1[s] *= sc;
    }
    // scatter dq -> qT (XTin dead: all P2 reads done at (12))
    #pragma unroll
    for (int s0 = 0; s0 < 8; s0 += 2) {
        unsigned hw, lw; bsplit2(dqA[s0], dqA[s0 + 1], hw, lw);
        int p0 = rrow * 8 + s0;
        int a0 = xswz(p0, ch), a1 = xswz(p0 + 1, ch);
        XTh[a0] = (short)hw; XTh[a1] = (short)(hw >> 16);
        XTl[a0] = (short)lw; XTl[a1] = (short)(lw >> 16);
    }
    {
        int cg = 32 + ch;
        #pragma unroll
        for (int s0 = 0; s0 < 8; s0 += 2) {
            unsigned hw, lw; bsplit2(dqB[s0], dqB[s0 + 1], hw, lw);
            int p0 = rrow * 8 + s0;
            int a0 = xswz(p0, cg), a1 = xswz(p0 + 1, cg);
            XTh[a0] = (short)hw; XTh[a1] = (short)(hw >> 16);
            XTl[a0] = (short)lw; XTl[a1] = (short)(lw >> 16);
        }
    }
    __syncthreads();   // (13) all scr reads done
    // scatter dk1 -> K1 (over dead scr)
    #pragma unroll
    for (int s0 = 0; s0 < 8; s0 += 2) {
        unsigned hw, lw; bsplit2(dk1[s0], dk1[s0 + 1], hw, lw);
        int p0 = rrow * 8 + s0;
        int a0 = kswz(p0, ch), a1 = kswz(p0 + 1, ch);
        K1h[a0] = (short)hw; K1h[a1] = (short)(hw >> 16);
        K1l[a0] = (short)lw; K1l[a1] = (short)(lw >> 16);
    }
    __syncthreads();   // (14) qT/kT ready

    // ---- P5: MFMA QK^T (M=i rows wv*16.., N=j all 64, K=c) + mask + softmax ----
    f32x4 at[4];
    #pragma unroll
    for (int nt = 0; nt < 4; ++nt) at[nt] = (f32x4){0.f, 0.f, 0.f, 0.f};
    {
        bf8 Ah[2], Al[2];
        #pragma unroll
        for (int kk = 0; kk < 2; ++kk) {
            int row = wv * 16 + col;
            int ad = row * 64 + ((kk * 32 + qo8) ^ (xkey(row) << 3));
            Ah[kk] = *(const bf8*)&XTh[ad];   // qT
            Al[kk] = *(const bf8*)&XTl[ad];
        }
        #pragma unroll
        for (int kk = 0; kk < 2; ++kk) {
            const short* Bph = kk ? K1h : K0h;
            const short* Bpl = kk ? K1l : K0l;
            #pragma unroll
            for (int nt = 0; nt < 4; ++nt) {
                int rowB = nt * 16 + col;
                int ad = kswz(rowB, qo8);
                bf8 Bh = *(const bf8*)&Bph[ad];
                bf8 Bl = *(const bf8*)&Bpl[ad];
                at[nt] = MFMA(Ah[kk], Bh, at[nt]);
                at[nt] = MFMA(Ah[kk], Bl, at[nt]);
                at[nt] = MFMA(Al[kk], Bh, at[nt]);
            }
        }
    }
    if (use_mask) {
        const int widx = n & 1023;
        const int hn_m = widx >> 5, wn_m = widx & 31;
        #pragma unroll
        for (int nt = 0; nt < 4; ++nt) {
            int j = nt * 16 + col;
            int rj = ((hn_m == 31) ? (((j >> 3) < 4) ? 1 : 2) : 0) * 3
                   + ((wn_m == 31) ? (((j & 7) < 4) ? 1 : 2) : 0);
            #pragma unroll
            for (int rg = 0; rg < 4; ++rg) {
                int i = wv * 16 + quad * 4 + rg;
                int ri = ((hn_m == 31) ? (((i >> 3) < 4) ? 1 : 2) : 0) * 3
                       + ((wn_m == 31) ? (((i & 7) < 4) ? 1 : 2) : 0);
                if (ri != rj) at[nt][rg] = at[nt][rg] - 100.f;
            }
        }
    }
    float Pv[4][4];
    #pragma unroll
    for (int rg = 0; rg < 4; ++rg) {
        float m = fmaxf(fmaxf(at[0][rg], at[1][rg]), fmaxf(at[2][rg], at[3][rg]));
        m = fmaxf(m, __shfl_xor(m, 1)); m = fmaxf(m, __shfl_xor(m, 2));
        m = fmaxf(m, __shfl_xor(m, 4)); m = fmaxf(m, __shfl_xor(m, 8));
        float e0 = __expf(at[0][rg] - m), e1 = __expf(at[1][rg] - m);
        float e2 = __expf(at[2][rg] - m), e3 = __expf(at[3][rg] - m);
        float s = e0 + e1 + e2 + e3;
        s += __shfl_xor(s, 1); s += __shfl_xor(s, 2);
        s += __shfl_xor(s, 4); s += __shfl_xor(s, 8);
        float is = 1.0f / s;
        Pv[0][rg] = e0 * is; Pv[1][rg] = e1 * is; Pv[2][rg] = e2 * is; Pv[3][rg] = e3 * is;
    }
    __syncthreads();   // (15) qT/kT reads done

    // ---- P6: M=c, N=j, K=i in two i-halves; acc in regs across halves. ----
    f32x4 av[2][2];
    #pragma unroll
    for (int mt = 0; mt < 2; ++mt)
        #pragma unroll
        for (int nt = 0; nt < 2; ++nt) av[mt][nt] = (f32x4){0.f, 0.f, 0.f, 0.f};
    #pragma unroll
    for (int ih = 0; ih < 2; ++ih) {
        // write vb half: threads whose rrow-half matches (i = rrow*8+s)
        if ((rrow >> 2) == ih) {
            int rl = rrow & 3;
            #pragma unroll
            for (int hf = 0; hf < 2; ++hf) {
                const float* dv = hf ? dvB : dvA;
                int cg = hf * 32 + ch;
                unsigned hw[4], lw[4];
                #pragma unroll
                for (int q2 = 0; q2 < 4; ++q2)
                    bsplit2(dv[2 * q2], dv[2 * q2 + 1], hw[q2], lw[q2]);
                int ad = kswz(cg, rl * 8);
                *(uint4*)&vbh[ad] = (uint4){hw[0], hw[1], hw[2], hw[3]};
                *(uint4*)&vbl[ad] = (uint4){lw[0], lw[1], lw[2], lw[3]};
            }
        }
        // write PT half: waves whose i-range matches (i = wv*16+quad*4+rg)
        if ((wv >> 1) == ih) {
            #pragma unroll
            for (int nt = 0; nt < 4; ++nt) {
                int j = nt * 16 + col;
                #pragma unroll
                for (int rp = 0; rp < 2; ++rp) {
                    unsigned hw, lw; bsplit2(Pv[nt][2 * rp], Pv[nt][2 * rp + 1], hw, lw);
                    int il = (wv & 1) * 16 + quad * 4 + 2 * rp;
                    int ad = kswz(j, il);
                    *(unsigned*)&PTf[ad] = hw; *(unsigned*)&PTg[ad] = lw;
                }
            }
        }
        __syncthreads();   // (16)/(18)
        {
            bf8 Ah[2], Al[2], Bh[2], Bl[2];
            #pragma unroll
            for (int mt = 0; mt < 2; ++mt) {
                int row = (mh * 2 + mt) * 16 + col;
                int ad = kswz(row, qo8);
                Ah[mt] = *(const bf8*)&vbh[ad];
                Al[mt] = *(const bf8*)&vbl[ad];
            }
            #pragma unroll
            for (int nt = 0; nt < 2; ++nt) {
                int rowB = (nh * 2 + nt) * 16 + col;
                int ad = kswz(rowB, qo8);
                Bh[nt] = *(const bf8*)&PTf[ad];
                Bl[nt] = *(const bf8*)&PTg[ad];
            }
            #pragma unroll
            for (int mt = 0; mt < 2; ++mt)
                #pragma unroll
                for (int nt = 0; nt < 2; ++nt) {
                    av[mt][nt] = MFMA(Ah[mt], Bh[nt], av[mt][nt]);
                    av[mt][nt] = MFMA(Ah[mt], Bl[nt], av[mt][nt]);
                    av[mt][nt] = MFMA(Al[mt], Bh[nt], av[mt][nt]);
                }
        }
        __syncthreads();   // (17)/(19) half reads done
    }
    // XTout writes (qT dead; visible to P7 after barrier (20))
    #pragma unroll
    for (int nt = 0; nt < 2; ++nt) {
        int j = (nh * 2 + nt) * 16 + col;
        #pragma unroll
        for (int mt = 0; mt < 2; ++mt) {
            int c0 = (mh * 2 + mt) * 16 + quad * 4;
            #pragma unroll
            for (int rp = 0; rp < 2; ++rp) {
                unsigned hw, lw; bsplit2(av[mt][nt][2 * rp], av[mt][nt][2 * rp + 1], hw, lw);
                int ad = j * 64 + ((c0 + 2 * rp) ^ (xkey(j) << 3));
                *(unsigned*)&XTh[ad] = hw;
                *(unsigned*)&XTl[ad] = lw;
            }
        }
    }
    // zero span for P7 OOB reads: smem[16384,16512) (vb/PT dead after (19))
    if (tid < 32) ((unsigned*)(smem + 16384))[tid] = 0u;
    __syncthreads();   // (20)

    // ---- P7: MFMA proj conv = 9 shifted GEMMs. M=p, N=oc, K=ic. OOB -> zero span
    //      via magic rows: 128 (XTh base) / 64 (XTl base) -> byte 16384, xkey=0. ----
    {
        f32x4 ap[2][2];
        #pragma unroll
        for (int mt = 0; mt < 2; ++mt)
            #pragma unroll
            for (int nt = 0; nt < 2; ++nt) ap[mt][nt] = (f32x4){0.f, 0.f, 0.f, 0.f};
        const int smc = col & 7;
        #pragma unroll 1
        for (int tap = 0; tap < 9; ++tap) {
            int dy = (tap >= 6) ? 1 : ((tap >= 3) ? 0 : -1);
            int dx = tap - (dy + 1) * 3 - 1;
            int ra_h[2], ra_l[2];
            #pragma unroll
            for (int mt = 0; mt < 2; ++mt) {
                int rr = (mh * 2 + mt) * 2 + (col >> 3) + dy;
                int ss = smc + dx;
                bool ok = ((unsigned)rr < 8u) && ((unsigned)ss < 8u);
                int row = rr * 8 + ss;
                ra_h[mt] = ok ? row : 128;
                ra_l[mt] = ok ? row : 64;
            }
            #pragma unroll
            for (int kk = 0; kk < 2; ++kk) {
                bf8 Bh[2], Bl[2], Ah[2], Al[2];
                #pragma unroll
                for (int nt = 0; nt < 2; ++nt) {
                    int bi = (((tap * 2 + kk) * 4 + (nh * 2 + nt)) * 64 + lane) * 8;
                    Bh[nt] = *(const bf8*)&bph[bi];
                    Bl[nt] = *(const bf8*)&bpl[bi];
                }
                #pragma unroll
                for (int mt = 0; mt < 2; ++mt) {
                    int adh = ra_h[mt] * 64 + ((kk * 32 + qo8) ^ (xkey(ra_h[mt]) << 3));
                    int adl = ra_l[mt] * 64 + ((kk * 32 + qo8) ^ (xkey(ra_l[mt]) << 3));
                    Ah[mt] = *(const bf8*)&XTh[adh];
                    Al[mt] = *(const bf8*)&XTl[adl];
                }
                #pragma unroll
                for (int mt = 0; mt < 2; ++mt)
                    #pragma unroll
                    for (int nt = 0; nt < 2; ++nt) {
                        ap[mt][nt] = MFMA(Ah[mt], Bh[nt], ap[mt][nt]);
                        ap[mt][nt] = MFMA(Ah[mt], Bl[nt], ap[mt][nt]);
                        ap[mt][nt] = MFMA(Al[mt], Bh[nt], ap[mt][nt]);
                    }
            }
        }
        __syncthreads();   // (21) all tap reads (incl. zero span) done
        #pragma unroll
        for (int nt = 0; nt < 2; ++nt) {
            int oc = (nh * 2 + nt) * 16 + col;
            #pragma unroll
            for (int mt = 0; mt < 2; ++mt) {
                int p0 = (mh * 2 + mt) * 16 + quad * 4;
                *(f32x4*)&projo[jswz(oc, p0)] = ap[mt][nt];
            }
        }
    }
    __syncthreads();   // (22)

    // ---- P8: window reverse + roll, coalesced image-order stores ----
    #pragma unroll
    for (int k = 0; k < 16; ++k) {
        int o = tid + k * 256;
        int hi = o >> 11, r = (o >> 8) & 7, lo = (o >> 3) & 31, s = o & 7;
        int c2 = hi * 32 + lo;
        float v = projo[jswz(c2, r * 8 + s)];
        int h2 = t * 16 + hi * 8 + r, w2 = lo * 8 + s;
        out[base + (size_t)((h2 + roll) & 255) * 256 + ((w2 + roll) & 255)] = v;
    }
}

extern "C" void kernel_launch(void* const* d_in, const int* in_sizes, int n_in,
                              void* d_out, int out_size, void* d_ws, size_t ws_size,
                              hipStream_t stream)
{
    const float* x      = (const float*)d_in[0];
    const float* wqkv0  = (const float*)d_in[1];
    const float* wdw0   = (const float*)d_in[2];
    const float* wproj0 = (const float*)d_in[3];
    const float* wqkv1  = (const float*)d_in[4];
    const float* wdw1   = (const float*)d_in[5];
    const float* wproj1 = (const float*)d_in[6];
    float* out = (float*)d_out;

    float* tmp = (float*)d_ws;                       // 33,554,432 floats (134 MB)
    short* fb  = (short*)(tmp + 33554432);
    short* bq0h = fb;                                // 12288 each
    short* bq0l = fb + 12288;
    short* bq1h = fb + 24576;
    short* bq1l = fb + 36864;
    short* bp0h = fb + 49152;                        // 36864 each
    short* bp0l = fb + 86016;
    short* bp1h = fb + 122880;
    short* bp1l = fb + 159744;

    hipLaunchKernelGGL(k_fq, dim3(24), dim3(512), 0, stream, wqkv0, bq0h, bq0l);
    hipLaunchKernelGGL(k_fq, dim3(24), dim3(512), 0, stream, wqkv1, bq1h, bq1l);
    hipLaunchKernelGGL(k_fp, dim3(72), dim3(512), 0, stream, wproj0, bp0h, bp0l);
    hipLaunchKernelGGL(k_fp, dim3(72), dim3(512), 0, stream, wproj1, bp1h, bp1l);

    // pass 1: x -> tmp (no shift/mask/roll)
    hipLaunchKernelGGL(k_fused, dim3(8192), dim3(256), 0, stream,
                       x, bq0h, bq0l, wdw0, bp0h, bp0l, tmp, 0, 0, 0);
    // pass 2: tmp -> out (shift +4 read, Swin mask, roll +4 write)
    hipLaunchKernelGGL(k_fused, dim3(8192), dim3(256), 0, stream,
                       tmp, bq1h, bq1l, wdw1, bp1h, bp1l, out, 4, 1, 4);
}

// Round 6
// 732.171 us; speedup vs baseline: 1.3141x; 1.3141x over previous
//
#include <hip/hip_runtime.h>

// LocalAttention (Swin scrambled-window variant) — all four GEMMs on MFMA.
// Window map (verified pass R2/R3): n=b*1024+c*16+t ; c2=hi*32+lo ; p=r*8+s ;
// h=16t+8hi+r ; w=8lo+s ; mask index = n&1023.
// l2norm folds into k:  attn[i][j] = sum_c q[c][i] * (k[c][j]*0.125/(nq_c*nk_c)).
// Split-bf16 everywhere: x=hi+lo, D += Ah*Bh + Ah*Bl + Al*Bh (rel err ~2^-18).
//
// R8: 32768B LDS arena (5 blocks/CU worth): kT split K0/K1, scr overlays K1,
//     P6 as two i-halves with vb/PT half-pieces, zero-span magic rows for P7.
// R9: __launch_bounds__(256,4) — R8's (256,5) forced VGPR 48 -> scratch spills
//     (FETCH 66K->304K KB, WRITE 131K->571K KB, 4.4x HBM). Cap 128 lets the
//     allocator use its natural ~80; HW can still co-schedule 5 blocks/CU if
//     the emitted count lands <=96 (gfx9 occupancy table: 5 waves/EU @ 96).
//   Arena: R1[0,16384) XTin->qT->XTout ; R2[16384,32768) K0|K1(scr) -> vb|PT
//          halves -> zero-span+projo.
//   22 barriers.

typedef __attribute__((ext_vector_type(8))) short bf8;
typedef __attribute__((ext_vector_type(4))) float f32x4;
#define MFMA(a, b, c) __builtin_amdgcn_mfma_f32_16x16x32_bf16(a, b, c, 0, 0, 0)

__device__ __forceinline__ int xkey(int p) { return ((p >> 3) ^ p) & 7; }
// bf16 64-wide regions: row p, col c (0..63) -> short index
__device__ __forceinline__ int xswz(int p, int c) { return p * 64 + (c ^ (xkey(p) << 3)); }
// bf16 32-wide regions (kT halves, vb/PT halves): row r, col c (0..31)
__device__ __forceinline__ int kswz(int r, int c) {
    return r * 32 + (c ^ ((((r >> 3) ^ (r >> 1)) & 3) << 3));
}
// scr fp32 (32 ch): stride 64, granule-4 XOR (uniform for P2 store + dw stencil)
__device__ __forceinline__ int sswz(int ch, int p) {
    return ch * 64 + (p ^ (((ch >> 1) & 7) << 2));
}
// projo fp32 (64 ch): stride 64, granule-8 XOR (uniform store, 2-way P8 read)
__device__ __forceinline__ int jswz(int ch, int p) {
    return ch * 64 + (p ^ (((ch >> 1) & 7) << 3));
}

// packed 2xf32 -> 2xbf16 (RNE). No builtin on gfx950 — inline asm (T12/m240).
__device__ __forceinline__ unsigned cvtpk(float a, float b) {
    unsigned r;
    asm("v_cvt_pk_bf16_f32 %0, %1, %2" : "=v"(r) : "v"(a), "v"(b));
    return r;
}

__device__ __forceinline__ void bsplit(float f, short& h, short& l) {
    unsigned u = __float_as_uint(f);
    unsigned hb = (u + 0x7FFFu + ((u >> 16) & 1u)) >> 16;
    float hf = __uint_as_float(hb << 16);
    float r = f - hf;
    unsigned u2 = __float_as_uint(r);
    unsigned lb = (u2 + 0x7FFFu + ((u2 >> 16) & 1u)) >> 16;
    h = (short)hb; l = (short)lb;
}
// a in low half, b in high half. hi = RNE-bf16(x); lo = RNE-bf16(x - hi).
__device__ __forceinline__ void bsplit2(float a, float b, unsigned& hw, unsigned& lw) {
    hw = cvtpk(a, b);
    float ra = a - __uint_as_float(hw << 16);
    float rb = b - __uint_as_float(hw & 0xFFFF0000u);
    lw = cvtpk(ra, rb);
}

// ---- qkv 1x1 weight fragments: [kk(2)][tt(12)][lane(64)][j(8)]  B[n=oc][k=ic] ----
__global__ void k_fq(const float* __restrict__ wq, short* __restrict__ oh, short* __restrict__ ol) {
    int bx = blockIdx.x;                 // kk*12 + tt
    int kk = bx / 12, tt = bx % 12;
    int tid = threadIdx.x;               // 512
    int lane = tid >> 3, j = tid & 7;
    int oc = tt * 16 + (lane & 15);
    int ic = kk * 32 + ((lane >> 4) << 3) + j;
    short h, l; bsplit(wq[oc * 64 + ic], h, l);
    oh[bx * 512 + tid] = h; ol[bx * 512 + tid] = l;
}
// ---- proj 3x3 weight fragments: [tap(9)][kk(2)][tt(4)][lane(64)][j(8)] ----
__global__ void k_fp(const float* __restrict__ wp, short* __restrict__ oh, short* __restrict__ ol) {
    int bx = blockIdx.x;                 // tap*8 + kk*4 + tt
    int tap = bx >> 3, kk = (bx >> 2) & 1, tt = bx & 3;
    int tid = threadIdx.x;
    int lane = tid >> 3, j = tid & 7;
    int oc = tt * 16 + (lane & 15);
    int ic = kk * 32 + ((lane >> 4) << 3) + j;
    short h, l; bsplit(wp[(oc * 64 + ic) * 9 + tap], h, l);
    oh[bx * 512 + tid] = h; ol[bx * 512 + tid] = l;
}

// dw3x3 for ONE channel (local ch 0..31 in scr), one output row, zero pad.
__device__ __forceinline__ void dw_one(const float* scr, const float* wd,
                                       int ch, int row, float o[8]) {
    float w9[9];
    #pragma unroll
    for (int tp = 0; tp < 9; ++tp) w9[tp] = wd[tp];
    float e[3][10];
    #pragma unroll
    for (int k3 = 0; k3 < 3; ++k3) {
        int rr = row - 1 + k3;
        e[k3][0] = 0.f; e[k3][9] = 0.f;
        if ((unsigned)rr < 8u) {
            float4 a = *(const float4*)&scr[sswz(ch, rr * 8)];
            float4 b = *(const float4*)&scr[sswz(ch, rr * 8 + 4)];
            e[k3][1] = a.x; e[k3][2] = a.y; e[k3][3] = a.z; e[k3][4] = a.w;
            e[k3][5] = b.x; e[k3][6] = b.y; e[k3][7] = b.z; e[k3][8] = b.w;
        } else {
            #pragma unroll
            for (int q2 = 1; q2 < 9; ++q2) e[k3][q2] = 0.f;
        }
    }
    #pragma unroll
    for (int s = 0; s < 8; ++s) {
        float a = 0.f;
        #pragma unroll
        for (int k3 = 0; k3 < 3; ++k3)
            #pragma unroll
            for (int dx = 0; dx < 3; ++dx)
                a = fmaf(w9[k3 * 3 + dx], e[k3][s + dx], a);
        o[s] = a;
    }
}

__device__ __forceinline__ float norm8(const float d[8]) {
    float ss = 0.f;
    #pragma unroll
    for (int s = 0; s < 8; ++s) ss = fmaf(d[s], d[s], ss);
    ss += __shfl_xor(ss, 1); ss += __shfl_xor(ss, 2); ss += __shfl_xor(ss, 4);
    return fmaxf(sqrtf(ss), 1e-12f);
}

// P2 chunk: 64px x 32oc x 64ic MFMA 1x1, XTin -> scr.
// chunk selects oc-16-tile pair: 0,1=q ; 2,3=k ; 4,5=v (tt = chunk*2+nh).
__device__ __forceinline__ void p2_chunk32(const short* XTh, const short* XTl,
                                           const short* bqh, const short* bql,
                                           float* scr, int chunk,
                                           int mh, int nh, int col, int quad, int qo8, int lane)
{
    f32x4 acc[2];
    #pragma unroll
    for (int mt = 0; mt < 2; ++mt) acc[mt] = (f32x4){0.f, 0.f, 0.f, 0.f};
    #pragma unroll
    for (int kk = 0; kk < 2; ++kk) {
        bf8 Ah[2], Al[2];
        #pragma unroll
        for (int mt = 0; mt < 2; ++mt) {
            int row = (mh * 2 + mt) * 16 + col;
            int ad = row * 64 + ((kk * 32 + qo8) ^ (xkey(row) << 3));
            Ah[mt] = *(const bf8*)&XTh[ad];
            Al[mt] = *(const bf8*)&XTl[ad];
        }
        int tt = chunk * 2 + nh;
        bf8 Bh = *(const bf8*)&bqh[((kk * 12 + tt) * 64 + lane) * 8];
        bf8 Bl = *(const bf8*)&bql[((kk * 12 + tt) * 64 + lane) * 8];
        #pragma unroll
        for (int mt = 0; mt < 2; ++mt) {
            acc[mt] = MFMA(Ah[mt], Bh, acc[mt]);
            acc[mt] = MFMA(Ah[mt], Bl, acc[mt]);
            acc[mt] = MFMA(Al[mt], Bh, acc[mt]);
        }
    }
    #pragma unroll
    for (int mt = 0; mt < 2; ++mt) {
        int ocl = nh * 16 + col;
        int p0 = (mh * 2 + mt) * 16 + quad * 4;
        *(f32x4*)&scr[sswz(ocl, p0)] = acc[mt];
    }
}

__global__ __launch_bounds__(256, 4)
void k_fused(const float* __restrict__ in,
             const short* __restrict__ bqh, const short* __restrict__ bql,
             const float* __restrict__ wdw,
             const short* __restrict__ bph, const short* __restrict__ bpl,
             float* __restrict__ out, int shift, int use_mask, int roll)
{
    __shared__ __align__(16) char smem[32768];
    short* XTh = (short*)smem;                 // R1: XTin -> qT -> XTout (8KB)
    short* XTl = (short*)(smem + 8192);        //     (8KB)
    short* K0h = (short*)(smem + 16384);       // kT c<32 hi (4KB)
    short* K0l = (short*)(smem + 20480);       // kT c<32 lo (4KB)
    short* K1h = (short*)(smem + 24576);       // kT c>=32 hi (4KB)
    short* K1l = (short*)(smem + 28672);       // kT c>=32 lo (4KB)
    float* scr = (float*)(smem + 24576);       // overlays K1 during front (8KB)
    short* vbh = (short*)(smem + 16384);       // P6: vb half hi (4KB)
    short* vbl = (short*)(smem + 20480);       //     vb half lo (4KB)
    short* PTf = (short*)(smem + 24576);       //     PT half hi (4KB)
    short* PTg = (short*)(smem + 28672);       //     PT half lo (4KB)
    float* projo = (float*)(smem + 16384);     // after P7 (16KB; zero span at +0)

    const int tid = threadIdx.x, lane = tid & 63, wv = tid >> 6;
    const int col = lane & 15, quad = lane >> 4, qo8 = quad * 8;
    const int mh = wv & 1, nh = wv >> 1;
    const int ch = tid >> 3, rrow = tid & 7;   // DW map: 1 channel/thread
    const int n = blockIdx.x;
    const int b = n >> 10, c = (n >> 4) & 63, t = n & 15;
    const size_t base = ((size_t)(b * 64 + c)) << 16;

    // ---- P1: load window (shift folded), split via cvt_pk pairs, XTin[p][c2] ----
    #pragma unroll
    for (int k = 0; k < 16; k += 2) {
        int o0 = tid + k * 256, o1 = o0 + 256;
        int hi0 = o0 >> 11, r0 = (o0 >> 8) & 7, lo0 = (o0 >> 3) & 31, s0 = o0 & 7;
        int hi1 = o1 >> 11, r1 = (o1 >> 8) & 7, lo1 = (o1 >> 3) & 31, s1 = o1 & 7;
        float v0 = in[base + (size_t)(((t * 16 + hi0 * 8 + r0) + shift) & 255) * 256
                           + (((lo0 * 8 + s0) + shift) & 255)];
        float v1 = in[base + (size_t)(((t * 16 + hi1 * 8 + r1) + shift) & 255) * 256
                           + (((lo1 * 8 + s1) + shift) & 255)];
        unsigned hw, lw; bsplit2(v0, v1, hw, lw);
        int ad0 = xswz(r0 * 8 + s0, hi0 * 32 + lo0);
        int ad1 = xswz(r1 * 8 + s1, hi1 * 32 + lo1);
        XTh[ad0] = (short)hw; XTh[ad1] = (short)(hw >> 16);
        XTl[ad0] = (short)lw; XTl[ad1] = (short)(lw >> 16);
    }
    __syncthreads();   // (1)

    float dqA[8], dqB[8], dvA[8], dvB[8];
    float nqA, nqB;

    // ---- q0 (oc tiles 0,1) ----
    p2_chunk32(XTh, XTl, bqh, bql, scr, 0, mh, nh, col, quad, qo8, lane);
    __syncthreads();   // (2)
    dw_one(scr, wdw + ch * 9, ch, rrow, dqA);
    nqA = norm8(dqA);
    __syncthreads();   // (3)
    // ---- q1 (oc tiles 2,3) ----
    p2_chunk32(XTh, XTl, bqh, bql, scr, 1, mh, nh, col, quad, qo8, lane);
    __syncthreads();   // (4)
    dw_one(scr, wdw + (32 + ch) * 9, ch, rrow, dqB);
    nqB = norm8(dqB);
    __syncthreads();   // (5)
    // ---- v0 (oc tiles 8,9) ----
    p2_chunk32(XTh, XTl, bqh, bql, scr, 4, mh, nh, col, quad, qo8, lane);
    __syncthreads();   // (6)
    dw_one(scr, wdw + (128 + ch) * 9, ch, rrow, dvA);
    __syncthreads();   // (7)
    // ---- v1 (oc tiles 10,11) ----
    p2_chunk32(XTh, XTl, bqh, bql, scr, 5, mh, nh, col, quad, qo8, lane);
    __syncthreads();   // (8)
    dw_one(scr, wdw + (160 + ch) * 9, ch, rrow, dvB);
    __syncthreads();   // (9)
    // ---- k0 (oc tiles 4,5): dk -> regs, scatter -> K0 (disjoint from scr=K1) ----
    p2_chunk32(XTh, XTl, bqh, bql, scr, 2, mh, nh, col, quad, qo8, lane);
    __syncthreads();   // (10)
    {
        float dk[8];
        dw_one(scr, wdw + (64 + ch) * 9, ch, rrow, dk);
        float sc = 0.125f / (nqA * norm8(dk));
        #pragma unroll
        for (int s = 0; s < 8; ++s) dk[s] *= sc;
        #pragma unroll
        for (int s0 = 0; s0 < 8; s0 += 2) {
            unsigned hw, lw; bsplit2(dk[s0], dk[s0 + 1], hw, lw);
            int p0 = rrow * 8 + s0;
            int a0 = kswz(p0, ch), a1 = kswz(p0 + 1, ch);
            K0h[a0] = (short)hw; K0h[a1] = (short)(hw >> 16);
            K0l[a0] = (short)lw; K0l[a1] = (short)(lw >> 16);
        }
    }
    __syncthreads();   // (11)
    // ---- k1 (oc tiles 6,7): last XTin reader ----
    p2_chunk32(XTh, XTl, bqh, bql, scr, 3, mh, nh, col, quad, qo8, lane);
    __syncthreads();   // (12)
    float dk1[8];
    dw_one(scr, wdw + (96 + ch) * 9, ch, rrow, dk1);
    {
        float sc = 0.125f / (nqB * norm8(dk1));
        #pragma unroll
        for (int s = 0; s < 8; ++s) dk1[s] *= sc;
    }
    // scatter dq -> qT (XTin dead: all P2 reads done at (12))
    #pragma unroll
    for (int s0 = 0; s0 < 8; s0 += 2) {
        unsigned hw, lw; bsplit2(dqA[s0], dqA[s0 + 1], hw, lw);
        int p0 = rrow * 8 + s0;
        int a0 = xswz(p0, ch), a1 = xswz(p0 + 1, ch);
        XTh[a0] = (short)hw; XTh[a1] = (short)(hw >> 16);
        XTl[a0] = (short)lw; XTl[a1] = (short)(lw >> 16);
    }
    {
        int cg = 32 + ch;
        #pragma unroll
        for (int s0 = 0; s0 < 8; s0 += 2) {
            unsigned hw, lw; bsplit2(dqB[s0], dqB[s0 + 1], hw, lw);
            int p0 = rrow * 8 + s0;
            int a0 = xswz(p0, cg), a1 = xswz(p0 + 1, cg);
            XTh[a0] = (short)hw; XTh[a1] = (short)(hw >> 16);
            XTl[a0] = (short)lw; XTl[a1] = (short)(lw >> 16);
        }
    }
    __syncthreads();   // (13) all scr reads done
    // scatter dk1 -> K1 (over dead scr)
    #pragma unroll
    for (int s0 = 0; s0 < 8; s0 += 2) {
        unsigned hw, lw; bsplit2(dk1[s0], dk1[s0 + 1], hw, lw);
        int p0 = rrow * 8 + s0;
        int a0 = kswz(p0, ch), a1 = kswz(p0 + 1, ch);
        K1h[a0] = (short)hw; K1h[a1] = (short)(hw >> 16);
        K1l[a0] = (short)lw; K1l[a1] = (short)(lw >> 16);
    }
    __syncthreads();   // (14) qT/kT ready

    // ---- P5: MFMA QK^T (M=i rows wv*16.., N=j all 64, K=c) + mask + softmax ----
    f32x4 at[4];
    #pragma unroll
    for (int nt = 0; nt < 4; ++nt) at[nt] = (f32x4){0.f, 0.f, 0.f, 0.f};
    {
        bf8 Ah[2], Al[2];
        #pragma unroll
        for (int kk = 0; kk < 2; ++kk) {
            int row = wv * 16 + col;
            int ad = row * 64 + ((kk * 32 + qo8) ^ (xkey(row) << 3));
            Ah[kk] = *(const bf8*)&XTh[ad];   // qT
            Al[kk] = *(const bf8*)&XTl[ad];
        }
        #pragma unroll
        for (int kk = 0; kk < 2; ++kk) {
            const short* Bph = kk ? K1h : K0h;
            const short* Bpl = kk ? K1l : K0l;
            #pragma unroll
            for (int nt = 0; nt < 4; ++nt) {
                int rowB = nt * 16 + col;
                int ad = kswz(rowB, qo8);
                bf8 Bh = *(const bf8*)&Bph[ad];
                bf8 Bl = *(const bf8*)&Bpl[ad];
                at[nt] = MFMA(Ah[kk], Bh, at[nt]);
                at[nt] = MFMA(Ah[kk], Bl, at[nt]);
                at[nt] = MFMA(Al[kk], Bh, at[nt]);
            }
        }
    }
    if (use_mask) {
        const int widx = n & 1023;
        const int hn_m = widx >> 5, wn_m = widx & 31;
        #pragma unroll
        for (int nt = 0; nt < 4; ++nt) {
            int j = nt * 16 + col;
            int rj = ((hn_m == 31) ? (((j >> 3) < 4) ? 1 : 2) : 0) * 3
                   + ((wn_m == 31) ? (((j & 7) < 4) ? 1 : 2) : 0);
            #pragma unroll
            for (int rg = 0; rg < 4; ++rg) {
                int i = wv * 16 + quad * 4 + rg;
                int ri = ((hn_m == 31) ? (((i >> 3) < 4) ? 1 : 2) : 0) * 3
                       + ((wn_m == 31) ? (((i & 7) < 4) ? 1 : 2) : 0);
                if (ri != rj) at[nt][rg] = at[nt][rg] - 100.f;
            }
        }
    }
    float Pv[4][4];
    #pragma unroll
    for (int rg = 0; rg < 4; ++rg) {
        float m = fmaxf(fmaxf(at[0][rg], at[1][rg]), fmaxf(at[2][rg], at[3][rg]));
        m = fmaxf(m, __shfl_xor(m, 1)); m = fmaxf(m, __shfl_xor(m, 2));
        m = fmaxf(m, __shfl_xor(m, 4)); m = fmaxf(m, __shfl_xor(m, 8));
        float e0 = __expf(at[0][rg] - m), e1 = __expf(at[1][rg] - m);
        float e2 = __expf(at[2][rg] - m), e3 = __expf(at[3][rg] - m);
        float s = e0 + e1 + e2 + e3;
        s += __shfl_xor(s, 1); s += __shfl_xor(s, 2);
        s += __shfl_xor(s, 4); s += __shfl_xor(s, 8);
        float is = 1.0f / s;
        Pv[0][rg] = e0 * is; Pv[1][rg] = e1 * is; Pv[2][rg] = e2 * is; Pv[3][rg] = e3 * is;
    }
    __syncthreads();   // (15) qT/kT reads done

    // ---- P6: M=c, N=j, K=i in two i-halves; acc in regs across halves. ----
    f32x4 av[2][2];
    #pragma unroll
    for (int mt = 0; mt < 2; ++mt)
        #pragma unroll
        for (int nt = 0; nt < 2; ++nt) av[mt][nt] = (f32x4){0.f, 0.f, 0.f, 0.f};
    #pragma unroll
    for (int ih = 0; ih < 2; ++ih) {
        // write vb half: threads whose rrow-half matches (i = rrow*8+s)
        if ((rrow >> 2) == ih) {
            int rl = rrow & 3;
            #pragma unroll
            for (int hf = 0; hf < 2; ++hf) {
                const float* dv = hf ? dvB : dvA;
                int cg = hf * 32 + ch;
                unsigned hw[4], lw[4];
                #pragma unroll
                for (int q2 = 0; q2 < 4; ++q2)
                    bsplit2(dv[2 * q2], dv[2 * q2 + 1], hw[q2], lw[q2]);
                int ad = kswz(cg, rl * 8);
                *(uint4*)&vbh[ad] = (uint4){hw[0], hw[1], hw[2], hw[3]};
                *(uint4*)&vbl[ad] = (uint4){lw[0], lw[1], lw[2], lw[3]};
            }
        }
        // write PT half: waves whose i-range matches (i = wv*16+quad*4+rg)
        if ((wv >> 1) == ih) {
            #pragma unroll
            for (int nt = 0; nt < 4; ++nt) {
                int j = nt * 16 + col;
                #pragma unroll
                for (int rp = 0; rp < 2; ++rp) {
                    unsigned hw, lw; bsplit2(Pv[nt][2 * rp], Pv[nt][2 * rp + 1], hw, lw);
                    int il = (wv & 1) * 16 + quad * 4 + 2 * rp;
                    int ad = kswz(j, il);
                    *(unsigned*)&PTf[ad] = hw; *(unsigned*)&PTg[ad] = lw;
                }
            }
        }
        __syncthreads();   // (16)/(18)
        {
            bf8 Ah[2], Al[2], Bh[2], Bl[2];
            #pragma unroll
            for (int mt = 0; mt < 2; ++mt) {
                int row = (mh * 2 + mt) * 16 + col;
                int ad = kswz(row, qo8);
                Ah[mt] = *(const bf8*)&vbh[ad];
                Al[mt] = *(const bf8*)&vbl[ad];
            }
            #pragma unroll
            for (int nt = 0; nt < 2; ++nt) {
                int rowB = (nh * 2 + nt) * 16 + col;
                int ad = kswz(rowB, qo8);
                Bh[nt] = *(const bf8*)&PTf[ad];
                Bl[nt] = *(const bf8*)&PTg[ad];
            }
            #pragma unroll
            for (int mt = 0; mt < 2; ++mt)
                #pragma unroll
                for (int nt = 0; nt < 2; ++nt) {
                    av[mt][nt] = MFMA(Ah[mt], Bh[nt], av[mt][nt]);
                    av[mt][nt] = MFMA(Ah[mt], Bl[nt], av[mt][nt]);
                    av[mt][nt] = MFMA(Al[mt], Bh[nt], av[mt][nt]);
                }
        }
        __syncthreads();   // (17)/(19) half reads done
    }
    // XTout writes (qT dead; visible to P7 after barrier (20))
    #pragma unroll
    for (int nt = 0; nt < 2; ++nt) {
        int j = (nh * 2 + nt) * 16 + col;
        #pragma unroll
        for (int mt = 0; mt < 2; ++mt) {
            int c0 = (mh * 2 + mt) * 16 + quad * 4;
            #pragma unroll
            for (int rp = 0; rp < 2; ++rp) {
                unsigned hw, lw; bsplit2(av[mt][nt][2 * rp], av[mt][nt][2 * rp + 1], hw, lw);
                int ad = j * 64 + ((c0 + 2 * rp) ^ (xkey(j) << 3));
                *(unsigned*)&XTh[ad] = hw;
                *(unsigned*)&XTl[ad] = lw;
            }
        }
    }
    // zero span for P7 OOB reads: smem[16384,16512) (vb/PT dead after (19))
    if (tid < 32) ((unsigned*)(smem + 16384))[tid] = 0u;
    __syncthreads();   // (20)

    // ---- P7: MFMA proj conv = 9 shifted GEMMs. M=p, N=oc, K=ic. OOB -> zero span
    //      via magic rows: 128 (XTh base) / 64 (XTl base) -> byte 16384, xkey=0. ----
    {
        f32x4 ap[2][2];
        #pragma unroll
        for (int mt = 0; mt < 2; ++mt)
            #pragma unroll
            for (int nt = 0; nt < 2; ++nt) ap[mt][nt] = (f32x4){0.f, 0.f, 0.f, 0.f};
        const int smc = col & 7;
        #pragma unroll 1
        for (int tap = 0; tap < 9; ++tap) {
            int dy = (tap >= 6) ? 1 : ((tap >= 3) ? 0 : -1);
            int dx = tap - (dy + 1) * 3 - 1;
            int ra_h[2], ra_l[2];
            #pragma unroll
            for (int mt = 0; mt < 2; ++mt) {
                int rr = (mh * 2 + mt) * 2 + (col >> 3) + dy;
                int ss = smc + dx;
                bool ok = ((unsigned)rr < 8u) && ((unsigned)ss < 8u);
                int row = rr * 8 + ss;
                ra_h[mt] = ok ? row : 128;
                ra_l[mt] = ok ? row : 64;
            }
            #pragma unroll
            for (int kk = 0; kk < 2; ++kk) {
                bf8 Bh[2], Bl[2], Ah[2], Al[2];
                #pragma unroll
                for (int nt = 0; nt < 2; ++nt) {
                    int bi = (((tap * 2 + kk) * 4 + (nh * 2 + nt)) * 64 + lane) * 8;
                    Bh[nt] = *(const bf8*)&bph[bi];
                    Bl[nt] = *(const bf8*)&bpl[bi];
                }
                #pragma unroll
                for (int mt = 0; mt < 2; ++mt) {
                    int adh = ra_h[mt] * 64 + ((kk * 32 + qo8) ^ (xkey(ra_h[mt]) << 3));
                    int adl = ra_l[mt] * 64 + ((kk * 32 + qo8) ^ (xkey(ra_l[mt]) << 3));
                    Ah[mt] = *(const bf8*)&XTh[adh];
                    Al[mt] = *(const bf8*)&XTl[adl];
                }
                #pragma unroll
                for (int mt = 0; mt < 2; ++mt)
                    #pragma unroll
                    for (int nt = 0; nt < 2; ++nt) {
                        ap[mt][nt] = MFMA(Ah[mt], Bh[nt], ap[mt][nt]);
                        ap[mt][nt] = MFMA(Ah[mt], Bl[nt], ap[mt][nt]);
                        ap[mt][nt] = MFMA(Al[mt], Bh[nt], ap[mt][nt]);
                    }
            }
        }
        __syncthreads();   // (21) all tap reads (incl. zero span) done
        #pragma unroll
        for (int nt = 0; nt < 2; ++nt) {
            int oc = (nh * 2 + nt) * 16 + col;
            #pragma unroll
            for (int mt = 0; mt < 2; ++mt) {
                int p0 = (mh * 2 + mt) * 16 + quad * 4;
                *(f32x4*)&projo[jswz(oc, p0)] = ap[mt][nt];
            }
        }
    }
    __syncthreads();   // (22)

    // ---- P8: window reverse + roll, coalesced image-order stores ----
    #pragma unroll
    for (int k = 0; k < 16; ++k) {
        int o = tid + k * 256;
        int hi = o >> 11, r = (o >> 8) & 7, lo = (o >> 3) & 31, s = o & 7;
        int c2 = hi * 32 + lo;
        float v = projo[jswz(c2, r * 8 + s)];
        int h2 = t * 16 + hi * 8 + r, w2 = lo * 8 + s;
        out[base + (size_t)((h2 + roll) & 255) * 256 + ((w2 + roll) & 255)] = v;
    }
}

extern "C" void kernel_launch(void* const* d_in, const int* in_sizes, int n_in,
                              void* d_out, int out_size, void* d_ws, size_t ws_size,
                              hipStream_t stream)
{
    const float* x      = (const float*)d_in[0];
    const float* wqkv0  = (const float*)d_in[1];
    const float* wdw0   = (const float*)d_in[2];
    const float* wproj0 = (const float*)d_in[3];
    const float* wqkv1  = (const float*)d_in[4];
    const float* wdw1   = (const float*)d_in[5];
    const float* wproj1 = (const float*)d_in[6];
    float* out = (float*)d_out;

    float* tmp = (float*)d_ws;                       // 33,554,432 floats (134 MB)
    short* fb  = (short*)(tmp + 33554432);
    short* bq0h = fb;                                // 12288 each
    short* bq0l = fb + 12288;
    short* bq1h = fb + 24576;
    short* bq1l = fb + 36864;
    short* bp0h = fb + 49152;                        // 36864 each
    short* bp0l = fb + 86016;
    short* bp1h = fb + 122880;
    short* bp1l = fb + 159744;

    hipLaunchKernelGGL(k_fq, dim3(24), dim3(512), 0, stream, wqkv0, bq0h, bq0l);
    hipLaunchKernelGGL(k_fq, dim3(24), dim3(512), 0, stream, wqkv1, bq1h, bq1l);
    hipLaunchKernelGGL(k_fp, dim3(72), dim3(512), 0, stream, wproj0, bp0h, bp0l);
    hipLaunchKernelGGL(k_fp, dim3(72), dim3(512), 0, stream, wproj1, bp1h, bp1l);

    // pass 1: x -> tmp (no shift/mask/roll)
    hipLaunchKernelGGL(k_fused, dim3(8192), dim3(256), 0, stream,
                       x, bq0h, bq0l, wdw0, bp0h, bp0l, tmp, 0, 0, 0);
    // pass 2: tmp -> out (shift +4 read, Swin mask, roll +4 write)
    hipLaunchKernelGGL(k_fused, dim3(8192), dim3(256), 0, stream,
                       tmp, bq1h, bq1l, wdw1, bp1h, bp1l, out, 4, 1, 4);
}

// Round 7
// 619.365 us; speedup vs baseline: 1.5534x; 1.1821x over previous
//
#include <hip/hip_runtime.h>

// LocalAttention (Swin scrambled-window variant) — all four GEMMs on MFMA.
// Window map (verified pass R2/R3): n=b*1024+c*16+t ; c2=hi*32+lo ; p=r*8+s ;
// h=16t+8hi+r ; w=8lo+s ; mask index = n&1023.
// l2norm folds into k:  attn[i][j] = sum_c q[c][i] * (k[c][j]*0.125/(nq_c*nk_c)).
// Split-bf16 everywhere: x=hi+lo, D += Ah*Bh + Ah*Bl + Al*Bh (rel err ~2^-18).
//
// R8: 32768B LDS arena (5 blocks/CU worth): kT split K0/K1, scr overlays K1,
//     P6 as two i-halves with vb/PT half-pieces, zero-span magic rows for P7.
// R9: __launch_bounds__(256,4) (R8's (256,5) forced VGPR 48 -> mass spills).
// R10: residual scratch (FETCH 149K/WRITE 303K vs 66K/131K clean) was localMem:
//     pointer-select `hf ? dvB : dvA` on allocas inside divergent P6 guard
//     blocks SROA (rule #20). Fix: preconvert dq/dv/Pv to packed bf16 words in
//     STRAIGHT-LINE code (qA*/qB*/vA*/vB*[4], Ph/Pl[4][2]); divergent writes
//     use only named words with static indices. Reg cost neutral.
//   Arena: R1[0,16384) XTin->qT->XTout ; R2[16384,32768) K0|K1(scr) -> vb|PT
//          halves -> zero-span+projo.
//   22 barriers.

typedef __attribute__((ext_vector_type(8))) short bf8;
typedef __attribute__((ext_vector_type(4))) float f32x4;
#define MFMA(a, b, c) __builtin_amdgcn_mfma_f32_16x16x32_bf16(a, b, c, 0, 0, 0)

__device__ __forceinline__ int xkey(int p) { return ((p >> 3) ^ p) & 7; }
// bf16 64-wide regions: row p, col c (0..63) -> short index
__device__ __forceinline__ int xswz(int p, int c) { return p * 64 + (c ^ (xkey(p) << 3)); }
// bf16 32-wide regions (kT halves, vb/PT halves): row r, col c (0..31)
__device__ __forceinline__ int kswz(int r, int c) {
    return r * 32 + (c ^ ((((r >> 3) ^ (r >> 1)) & 3) << 3));
}
// scr fp32 (32 ch): stride 64, granule-4 XOR (uniform for P2 store + dw stencil)
__device__ __forceinline__ int sswz(int ch, int p) {
    return ch * 64 + (p ^ (((ch >> 1) & 7) << 2));
}
// projo fp32 (64 ch): stride 64, granule-8 XOR (uniform store, 2-way P8 read)
__device__ __forceinline__ int jswz(int ch, int p) {
    return ch * 64 + (p ^ (((ch >> 1) & 7) << 3));
}

// packed 2xf32 -> 2xbf16 (RNE). No builtin on gfx950 — inline asm (T12/m240).
__device__ __forceinline__ unsigned cvtpk(float a, float b) {
    unsigned r;
    asm("v_cvt_pk_bf16_f32 %0, %1, %2" : "=v"(r) : "v"(a), "v"(b));
    return r;
}

__device__ __forceinline__ void bsplit(float f, short& h, short& l) {
    unsigned u = __float_as_uint(f);
    unsigned hb = (u + 0x7FFFu + ((u >> 16) & 1u)) >> 16;
    float hf = __uint_as_float(hb << 16);
    float r = f - hf;
    unsigned u2 = __float_as_uint(r);
    unsigned lb = (u2 + 0x7FFFu + ((u2 >> 16) & 1u)) >> 16;
    h = (short)hb; l = (short)lb;
}
// a in low half, b in high half. hi = RNE-bf16(x); lo = RNE-bf16(x - hi).
__device__ __forceinline__ void bsplit2(float a, float b, unsigned& hw, unsigned& lw) {
    hw = cvtpk(a, b);
    float ra = a - __uint_as_float(hw << 16);
    float rb = b - __uint_as_float(hw & 0xFFFF0000u);
    lw = cvtpk(ra, rb);
}

// ---- qkv 1x1 weight fragments: [kk(2)][tt(12)][lane(64)][j(8)]  B[n=oc][k=ic] ----
__global__ void k_fq(const float* __restrict__ wq, short* __restrict__ oh, short* __restrict__ ol) {
    int bx = blockIdx.x;                 // kk*12 + tt
    int kk = bx / 12, tt = bx % 12;
    int tid = threadIdx.x;               // 512
    int lane = tid >> 3, j = tid & 7;
    int oc = tt * 16 + (lane & 15);
    int ic = kk * 32 + ((lane >> 4) << 3) + j;
    short h, l; bsplit(wq[oc * 64 + ic], h, l);
    oh[bx * 512 + tid] = h; ol[bx * 512 + tid] = l;
}
// ---- proj 3x3 weight fragments: [tap(9)][kk(2)][tt(4)][lane(64)][j(8)] ----
__global__ void k_fp(const float* __restrict__ wp, short* __restrict__ oh, short* __restrict__ ol) {
    int bx = blockIdx.x;                 // tap*8 + kk*4 + tt
    int tap = bx >> 3, kk = (bx >> 2) & 1, tt = bx & 3;
    int tid = threadIdx.x;
    int lane = tid >> 3, j = tid & 7;
    int oc = tt * 16 + (lane & 15);
    int ic = kk * 32 + ((lane >> 4) << 3) + j;
    short h, l; bsplit(wp[(oc * 64 + ic) * 9 + tap], h, l);
    oh[bx * 512 + tid] = h; ol[bx * 512 + tid] = l;
}

// dw3x3 for ONE channel (local ch 0..31 in scr), one output row, zero pad.
__device__ __forceinline__ void dw_one(const float* scr, const float* wd,
                                       int ch, int row, float o[8]) {
    float w9[9];
    #pragma unroll
    for (int tp = 0; tp < 9; ++tp) w9[tp] = wd[tp];
    float e[3][10];
    #pragma unroll
    for (int k3 = 0; k3 < 3; ++k3) {
        int rr = row - 1 + k3;
        e[k3][0] = 0.f; e[k3][9] = 0.f;
        if ((unsigned)rr < 8u) {
            float4 a = *(const float4*)&scr[sswz(ch, rr * 8)];
            float4 b = *(const float4*)&scr[sswz(ch, rr * 8 + 4)];
            e[k3][1] = a.x; e[k3][2] = a.y; e[k3][3] = a.z; e[k3][4] = a.w;
            e[k3][5] = b.x; e[k3][6] = b.y; e[k3][7] = b.z; e[k3][8] = b.w;
        } else {
            #pragma unroll
            for (int q2 = 1; q2 < 9; ++q2) e[k3][q2] = 0.f;
        }
    }
    #pragma unroll
    for (int s = 0; s < 8; ++s) {
        float a = 0.f;
        #pragma unroll
        for (int k3 = 0; k3 < 3; ++k3)
            #pragma unroll
            for (int dx = 0; dx < 3; ++dx)
                a = fmaf(w9[k3 * 3 + dx], e[k3][s + dx], a);
        o[s] = a;
    }
}

__device__ __forceinline__ float norm8(const float d[8]) {
    float ss = 0.f;
    #pragma unroll
    for (int s = 0; s < 8; ++s) ss = fmaf(d[s], d[s], ss);
    ss += __shfl_xor(ss, 1); ss += __shfl_xor(ss, 2); ss += __shfl_xor(ss, 4);
    return fmaxf(sqrtf(ss), 1e-12f);
}

// P2 chunk: 64px x 32oc x 64ic MFMA 1x1, XTin -> scr.
// chunk selects oc-16-tile pair: 0,1=q ; 2,3=k ; 4,5=v (tt = chunk*2+nh).
__device__ __forceinline__ void p2_chunk32(const short* XTh, const short* XTl,
                                           const short* bqh, const short* bql,
                                           float* scr, int chunk,
                                           int mh, int nh, int col, int quad, int qo8, int lane)
{
    f32x4 acc[2];
    #pragma unroll
    for (int mt = 0; mt < 2; ++mt) acc[mt] = (f32x4){0.f, 0.f, 0.f, 0.f};
    #pragma unroll
    for (int kk = 0; kk < 2; ++kk) {
        bf8 Ah[2], Al[2];
        #pragma unroll
        for (int mt = 0; mt < 2; ++mt) {
            int row = (mh * 2 + mt) * 16 + col;
            int ad = row * 64 + ((kk * 32 + qo8) ^ (xkey(row) << 3));
            Ah[mt] = *(const bf8*)&XTh[ad];
            Al[mt] = *(const bf8*)&XTl[ad];
        }
        int tt = chunk * 2 + nh;
        bf8 Bh = *(const bf8*)&bqh[((kk * 12 + tt) * 64 + lane) * 8];
        bf8 Bl = *(const bf8*)&bql[((kk * 12 + tt) * 64 + lane) * 8];
        #pragma unroll
        for (int mt = 0; mt < 2; ++mt) {
            acc[mt] = MFMA(Ah[mt], Bh, acc[mt]);
            acc[mt] = MFMA(Ah[mt], Bl, acc[mt]);
            acc[mt] = MFMA(Al[mt], Bh, acc[mt]);
        }
    }
    #pragma unroll
    for (int mt = 0; mt < 2; ++mt) {
        int ocl = nh * 16 + col;
        int p0 = (mh * 2 + mt) * 16 + quad * 4;
        *(f32x4*)&scr[sswz(ocl, p0)] = acc[mt];
    }
}

__global__ __launch_bounds__(256, 4)
void k_fused(const float* __restrict__ in,
             const short* __restrict__ bqh, const short* __restrict__ bql,
             const float* __restrict__ wdw,
             const short* __restrict__ bph, const short* __restrict__ bpl,
             float* __restrict__ out, int shift, int use_mask, int roll)
{
    __shared__ __align__(16) char smem[32768];
    short* XTh = (short*)smem;                 // R1: XTin -> qT -> XTout (8KB)
    short* XTl = (short*)(smem + 8192);        //     (8KB)
    short* K0h = (short*)(smem + 16384);       // kT c<32 hi (4KB)
    short* K0l = (short*)(smem + 20480);       // kT c<32 lo (4KB)
    short* K1h = (short*)(smem + 24576);       // kT c>=32 hi (4KB)
    short* K1l = (short*)(smem + 28672);       // kT c>=32 lo (4KB)
    float* scr = (float*)(smem + 24576);       // overlays K1 during front (8KB)
    short* vbh = (short*)(smem + 16384);       // P6: vb half hi (4KB)
    short* vbl = (short*)(smem + 20480);       //     vb half lo (4KB)
    short* PTf = (short*)(smem + 24576);       //     PT half hi (4KB)
    short* PTg = (short*)(smem + 28672);       //     PT half lo (4KB)
    float* projo = (float*)(smem + 16384);     // after P7 (16KB; zero span at +0)

    const int tid = threadIdx.x, lane = tid & 63, wv = tid >> 6;
    const int col = lane & 15, quad = lane >> 4, qo8 = quad * 8;
    const int mh = wv & 1, nh = wv >> 1;
    const int ch = tid >> 3, rrow = tid & 7;   // DW map: 1 channel/thread
    const int n = blockIdx.x;
    const int b = n >> 10, c = (n >> 4) & 63, t = n & 15;
    const size_t base = ((size_t)(b * 64 + c)) << 16;

    // ---- P1: load window (shift folded), split via cvt_pk pairs, XTin[p][c2] ----
    #pragma unroll
    for (int k = 0; k < 16; k += 2) {
        int o0 = tid + k * 256, o1 = o0 + 256;
        int hi0 = o0 >> 11, r0 = (o0 >> 8) & 7, lo0 = (o0 >> 3) & 31, s0 = o0 & 7;
        int hi1 = o1 >> 11, r1 = (o1 >> 8) & 7, lo1 = (o1 >> 3) & 31, s1 = o1 & 7;
        float v0 = in[base + (size_t)(((t * 16 + hi0 * 8 + r0) + shift) & 255) * 256
                           + (((lo0 * 8 + s0) + shift) & 255)];
        float v1 = in[base + (size_t)(((t * 16 + hi1 * 8 + r1) + shift) & 255) * 256
                           + (((lo1 * 8 + s1) + shift) & 255)];
        unsigned hw, lw; bsplit2(v0, v1, hw, lw);
        int ad0 = xswz(r0 * 8 + s0, hi0 * 32 + lo0);
        int ad1 = xswz(r1 * 8 + s1, hi1 * 32 + lo1);
        XTh[ad0] = (short)hw; XTh[ad1] = (short)(hw >> 16);
        XTl[ad0] = (short)lw; XTl[ad1] = (short)(lw >> 16);
    }
    __syncthreads();   // (1)

    // preconverted packed bf16 words (straight-line SROA-safe; rule #20)
    unsigned qAh[4], qAl[4], qBh[4], qBl[4];
    unsigned vAh[4], vAl[4], vBh[4], vBl[4];
    float nqA, nqB;

    // ---- q0 (oc tiles 0,1) ----
    p2_chunk32(XTh, XTl, bqh, bql, scr, 0, mh, nh, col, quad, qo8, lane);
    __syncthreads();   // (2)
    {
        float dq[8];
        dw_one(scr, wdw + ch * 9, ch, rrow, dq);
        nqA = norm8(dq);
        #pragma unroll
        for (int q2 = 0; q2 < 4; ++q2) bsplit2(dq[2 * q2], dq[2 * q2 + 1], qAh[q2], qAl[q2]);
    }
    __syncthreads();   // (3)
    // ---- q1 (oc tiles 2,3) ----
    p2_chunk32(XTh, XTl, bqh, bql, scr, 1, mh, nh, col, quad, qo8, lane);
    __syncthreads();   // (4)
    {
        float dq[8];
        dw_one(scr, wdw + (32 + ch) * 9, ch, rrow, dq);
        nqB = norm8(dq);
        #pragma unroll
        for (int q2 = 0; q2 < 4; ++q2) bsplit2(dq[2 * q2], dq[2 * q2 + 1], qBh[q2], qBl[q2]);
    }
    __syncthreads();   // (5)
    // ---- v0 (oc tiles 8,9) ----
    p2_chunk32(XTh, XTl, bqh, bql, scr, 4, mh, nh, col, quad, qo8, lane);
    __syncthreads();   // (6)
    {
        float dv[8];
        dw_one(scr, wdw + (128 + ch) * 9, ch, rrow, dv);
        #pragma unroll
        for (int q2 = 0; q2 < 4; ++q2) bsplit2(dv[2 * q2], dv[2 * q2 + 1], vAh[q2], vAl[q2]);
    }
    __syncthreads();   // (7)
    // ---- v1 (oc tiles 10,11) ----
    p2_chunk32(XTh, XTl, bqh, bql, scr, 5, mh, nh, col, quad, qo8, lane);
    __syncthreads();   // (8)
    {
        float dv[8];
        dw_one(scr, wdw + (160 + ch) * 9, ch, rrow, dv);
        #pragma unroll
        for (int q2 = 0; q2 < 4; ++q2) bsplit2(dv[2 * q2], dv[2 * q2 + 1], vBh[q2], vBl[q2]);
    }
    __syncthreads();   // (9)
    // ---- k0 (oc tiles 4,5): dk -> regs, scatter -> K0 (disjoint from scr=K1) ----
    p2_chunk32(XTh, XTl, bqh, bql, scr, 2, mh, nh, col, quad, qo8, lane);
    __syncthreads();   // (10)
    {
        float dk[8];
        dw_one(scr, wdw + (64 + ch) * 9, ch, rrow, dk);
        float sc = 0.125f / (nqA * norm8(dk));
        #pragma unroll
        for (int s = 0; s < 8; ++s) dk[s] *= sc;
        #pragma unroll
        for (int s0 = 0; s0 < 8; s0 += 2) {
            unsigned hw, lw; bsplit2(dk[s0], dk[s0 + 1], hw, lw);
            int p0 = rrow * 8 + s0;
            int a0 = kswz(p0, ch), a1 = kswz(p0 + 1, ch);
            K0h[a0] = (short)hw; K0h[a1] = (short)(hw >> 16);
            K0l[a0] = (short)lw; K0l[a1] = (short)(lw >> 16);
        }
    }
    __syncthreads();   // (11)
    // ---- k1 (oc tiles 6,7): last XTin reader ----
    p2_chunk32(XTh, XTl, bqh, bql, scr, 3, mh, nh, col, quad, qo8, lane);
    __syncthreads();   // (12)
    unsigned k1h[4], k1l[4];
    {
        float dk[8];
        dw_one(scr, wdw + (96 + ch) * 9, ch, rrow, dk);
        float sc = 0.125f / (nqB * norm8(dk));
        #pragma unroll
        for (int s = 0; s < 8; ++s) dk[s] *= sc;
        #pragma unroll
        for (int q2 = 0; q2 < 4; ++q2) bsplit2(dk[2 * q2], dk[2 * q2 + 1], k1h[q2], k1l[q2]);
    }
    // scatter dq -> qT (XTin dead: all P2 reads done at (12))
    #pragma unroll
    for (int q2 = 0; q2 < 4; ++q2) {
        int p0 = rrow * 8 + 2 * q2;
        int a0 = xswz(p0, ch), a1 = xswz(p0 + 1, ch);
        XTh[a0] = (short)qAh[q2]; XTh[a1] = (short)(qAh[q2] >> 16);
        XTl[a0] = (short)qAl[q2]; XTl[a1] = (short)(qAl[q2] >> 16);
        int cg = 32 + ch;
        int b0 = xswz(p0, cg), b1 = xswz(p0 + 1, cg);
        XTh[b0] = (short)qBh[q2]; XTh[b1] = (short)(qBh[q2] >> 16);
        XTl[b0] = (short)qBl[q2]; XTl[b1] = (short)(qBl[q2] >> 16);
    }
    __syncthreads();   // (13) all scr reads done
    // scatter dk1 -> K1 (over dead scr)
    #pragma unroll
    for (int q2 = 0; q2 < 4; ++q2) {
        int p0 = rrow * 8 + 2 * q2;
        int a0 = kswz(p0, ch), a1 = kswz(p0 + 1, ch);
        K1h[a0] = (short)k1h[q2]; K1h[a1] = (short)(k1h[q2] >> 16);
        K1l[a0] = (short)k1l[q2]; K1l[a1] = (short)(k1l[q2] >> 16);
    }
    __syncthreads();   // (14) qT/kT ready

    // ---- P5: MFMA QK^T (M=i rows wv*16.., N=j all 64, K=c) + mask + softmax ----
    f32x4 at[4];
    #pragma unroll
    for (int nt = 0; nt < 4; ++nt) at[nt] = (f32x4){0.f, 0.f, 0.f, 0.f};
    {
        bf8 Ah[2], Al[2];
        #pragma unroll
        for (int kk = 0; kk < 2; ++kk) {
            int row = wv * 16 + col;
            int ad = row * 64 + ((kk * 32 + qo8) ^ (xkey(row) << 3));
            Ah[kk] = *(const bf8*)&XTh[ad];   // qT
            Al[kk] = *(const bf8*)&XTl[ad];
        }
        #pragma unroll
        for (int kk = 0; kk < 2; ++kk) {
            const short* Bph = kk ? K1h : K0h;
            const short* Bpl = kk ? K1l : K0l;
            #pragma unroll
            for (int nt = 0; nt < 4; ++nt) {
                int rowB = nt * 16 + col;
                int ad = kswz(rowB, qo8);
                bf8 Bh = *(const bf8*)&Bph[ad];
                bf8 Bl = *(const bf8*)&Bpl[ad];
                at[nt] = MFMA(Ah[kk], Bh, at[nt]);
                at[nt] = MFMA(Ah[kk], Bl, at[nt]);
                at[nt] = MFMA(Al[kk], Bh, at[nt]);
            }
        }
    }
    if (use_mask) {
        const int widx = n & 1023;
        const int hn_m = widx >> 5, wn_m = widx & 31;
        #pragma unroll
        for (int nt = 0; nt < 4; ++nt) {
            int j = nt * 16 + col;
            int rj = ((hn_m == 31) ? (((j >> 3) < 4) ? 1 : 2) : 0) * 3
                   + ((wn_m == 31) ? (((j & 7) < 4) ? 1 : 2) : 0);
            #pragma unroll
            for (int rg = 0; rg < 4; ++rg) {
                int i = wv * 16 + quad * 4 + rg;
                int ri = ((hn_m == 31) ? (((i >> 3) < 4) ? 1 : 2) : 0) * 3
                       + ((wn_m == 31) ? (((i & 7) < 4) ? 1 : 2) : 0);
                if (ri != rj) at[nt][rg] = at[nt][rg] - 100.f;
            }
        }
    }
    unsigned Ph[4][2], Pl[4][2];
    {
        float Pv[4][4];
        #pragma unroll
        for (int rg = 0; rg < 4; ++rg) {
            float m = fmaxf(fmaxf(at[0][rg], at[1][rg]), fmaxf(at[2][rg], at[3][rg]));
            m = fmaxf(m, __shfl_xor(m, 1)); m = fmaxf(m, __shfl_xor(m, 2));
            m = fmaxf(m, __shfl_xor(m, 4)); m = fmaxf(m, __shfl_xor(m, 8));
            float e0 = __expf(at[0][rg] - m), e1 = __expf(at[1][rg] - m);
            float e2 = __expf(at[2][rg] - m), e3 = __expf(at[3][rg] - m);
            float s = e0 + e1 + e2 + e3;
            s += __shfl_xor(s, 1); s += __shfl_xor(s, 2);
            s += __shfl_xor(s, 4); s += __shfl_xor(s, 8);
            float is = 1.0f / s;
            Pv[0][rg] = e0 * is; Pv[1][rg] = e1 * is; Pv[2][rg] = e2 * is; Pv[3][rg] = e3 * is;
        }
        // preconvert straight-line (divergent PT-write uses only these words)
        #pragma unroll
        for (int nt = 0; nt < 4; ++nt)
            #pragma unroll
            for (int rp = 0; rp < 2; ++rp)
                bsplit2(Pv[nt][2 * rp], Pv[nt][2 * rp + 1], Ph[nt][rp], Pl[nt][rp]);
    }
    __syncthreads();   // (15) qT/kT reads done

    // ---- P6: M=c, N=j, K=i in two i-halves; acc in regs across halves. ----
    f32x4 av[2][2];
    #pragma unroll
    for (int mt = 0; mt < 2; ++mt)
        #pragma unroll
        for (int nt = 0; nt < 2; ++nt) av[mt][nt] = (f32x4){0.f, 0.f, 0.f, 0.f};
    #pragma unroll
    for (int ih = 0; ih < 2; ++ih) {
        // write vb half: threads whose rrow-half matches (i = rrow*8+s)
        if ((rrow >> 2) == ih) {
            int rl = rrow & 3;
            int adA = kswz(ch, rl * 8);
            *(uint4*)&vbh[adA] = (uint4){vAh[0], vAh[1], vAh[2], vAh[3]};
            *(uint4*)&vbl[adA] = (uint4){vAl[0], vAl[1], vAl[2], vAl[3]};
            int adB = kswz(32 + ch, rl * 8);
            *(uint4*)&vbh[adB] = (uint4){vBh[0], vBh[1], vBh[2], vBh[3]};
            *(uint4*)&vbl[adB] = (uint4){vBl[0], vBl[1], vBl[2], vBl[3]};
        }
        // write PT half: waves whose i-range matches (i = wv*16+quad*4+rg)
        if ((wv >> 1) == ih) {
            #pragma unroll
            for (int nt = 0; nt < 4; ++nt) {
                int j = nt * 16 + col;
                #pragma unroll
                for (int rp = 0; rp < 2; ++rp) {
                    int il = (wv & 1) * 16 + quad * 4 + 2 * rp;
                    int ad = kswz(j, il);
                    *(unsigned*)&PTf[ad] = Ph[nt][rp];
                    *(unsigned*)&PTg[ad] = Pl[nt][rp];
                }
            }
        }
        __syncthreads();   // (16)/(18)
        {
            bf8 Ah[2], Al[2], Bh[2], Bl[2];
            #pragma unroll
            for (int mt = 0; mt < 2; ++mt) {
                int row = (mh * 2 + mt) * 16 + col;
                int ad = kswz(row, qo8);
                Ah[mt] = *(const bf8*)&vbh[ad];
                Al[mt] = *(const bf8*)&vbl[ad];
            }
            #pragma unroll
            for (int nt = 0; nt < 2; ++nt) {
                int rowB = (nh * 2 + nt) * 16 + col;
                int ad = kswz(rowB, qo8);
                Bh[nt] = *(const bf8*)&PTf[ad];
                Bl[nt] = *(const bf8*)&PTg[ad];
            }
            #pragma unroll
            for (int mt = 0; mt < 2; ++mt)
                #pragma unroll
                for (int nt = 0; nt < 2; ++nt) {
                    av[mt][nt] = MFMA(Ah[mt], Bh[nt], av[mt][nt]);
                    av[mt][nt] = MFMA(Ah[mt], Bl[nt], av[mt][nt]);
                    av[mt][nt] = MFMA(Al[mt], Bh[nt], av[mt][nt]);
                }
        }
        __syncthreads();   // (17)/(19) half reads done
    }
    // XTout writes (qT dead; visible to P7 after barrier (20))
    #pragma unroll
    for (int nt = 0; nt < 2; ++nt) {
        int j = (nh * 2 + nt) * 16 + col;
        #pragma unroll
        for (int mt = 0; mt < 2; ++mt) {
            int c0 = (mh * 2 + mt) * 16 + quad * 4;
            #pragma unroll
            for (int rp = 0; rp < 2; ++rp) {
                unsigned hw, lw; bsplit2(av[mt][nt][2 * rp], av[mt][nt][2 * rp + 1], hw, lw);
                int ad = j * 64 + ((c0 + 2 * rp) ^ (xkey(j) << 3));
                *(unsigned*)&XTh[ad] = hw;
                *(unsigned*)&XTl[ad] = lw;
            }
        }
    }
    // zero span for P7 OOB reads: smem[16384,16512) (vb/PT dead after (19))
    if (tid < 32) ((unsigned*)(smem + 16384))[tid] = 0u;
    __syncthreads();   // (20)

    // ---- P7: MFMA proj conv = 9 shifted GEMMs. M=p, N=oc, K=ic. OOB -> zero span
    //      via magic rows: 128 (XTh base) / 64 (XTl base) -> byte 16384, xkey=0. ----
    {
        f32x4 ap[2][2];
        #pragma unroll
        for (int mt = 0; mt < 2; ++mt)
            #pragma unroll
            for (int nt = 0; nt < 2; ++nt) ap[mt][nt] = (f32x4){0.f, 0.f, 0.f, 0.f};
        const int smc = col & 7;
        #pragma unroll 1
        for (int tap = 0; tap < 9; ++tap) {
            int dy = (tap >= 6) ? 1 : ((tap >= 3) ? 0 : -1);
            int dx = tap - (dy + 1) * 3 - 1;
            int ra_h[2], ra_l[2];
            #pragma unroll
            for (int mt = 0; mt < 2; ++mt) {
                int rr = (mh * 2 + mt) * 2 + (col >> 3) + dy;
                int ss = smc + dx;
                bool ok = ((unsigned)rr < 8u) && ((unsigned)ss < 8u);
                int row = rr * 8 + ss;
                ra_h[mt] = ok ? row : 128;
                ra_l[mt] = ok ? row : 64;
            }
            #pragma unroll
            for (int kk = 0; kk < 2; ++kk) {
                bf8 Bh[2], Bl[2], Ah[2], Al[2];
                #pragma unroll
                for (int nt = 0; nt < 2; ++nt) {
                    int bi = (((tap * 2 + kk) * 4 + (nh * 2 + nt)) * 64 + lane) * 8;
                    Bh[nt] = *(const bf8*)&bph[bi];
                    Bl[nt] = *(const bf8*)&bpl[bi];
                }
                #pragma unroll
                for (int mt = 0; mt < 2; ++mt) {
                    int adh = ra_h[mt] * 64 + ((kk * 32 + qo8) ^ (xkey(ra_h[mt]) << 3));
                    int adl = ra_l[mt] * 64 + ((kk * 32 + qo8) ^ (xkey(ra_l[mt]) << 3));
                    Ah[mt] = *(const bf8*)&XTh[adh];
                    Al[mt] = *(const bf8*)&XTl[adl];
                }
                #pragma unroll
                for (int mt = 0; mt < 2; ++mt)
                    #pragma unroll
                    for (int nt = 0; nt < 2; ++nt) {
                        ap[mt][nt] = MFMA(Ah[mt], Bh[nt], ap[mt][nt]);
                        ap[mt][nt] = MFMA(Ah[mt], Bl[nt], ap[mt][nt]);
                        ap[mt][nt] = MFMA(Al[mt], Bh[nt], ap[mt][nt]);
                    }
            }
        }
        __syncthreads();   // (21) all tap reads (incl. zero span) done
        #pragma unroll
        for (int nt = 0; nt < 2; ++nt) {
            int oc = (nh * 2 + nt) * 16 + col;
            #pragma unroll
            for (int mt = 0; mt < 2; ++mt) {
                int p0 = (mh * 2 + mt) * 16 + quad * 4;
                *(f32x4*)&projo[jswz(oc, p0)] = ap[mt][nt];
            }
        }
    }
    __syncthreads();   // (22)

    // ---- P8: window reverse + roll, coalesced image-order stores ----
    #pragma unroll
    for (int k = 0; k < 16; ++k) {
        int o = tid + k * 256;
        int hi = o >> 11, r = (o >> 8) & 7, lo = (o >> 3) & 31, s = o & 7;
        int c2 = hi * 32 + lo;
        float v = projo[jswz(c2, r * 8 + s)];
        int h2 = t * 16 + hi * 8 + r, w2 = lo * 8 + s;
        out[base + (size_t)((h2 + roll) & 255) * 256 + ((w2 + roll) & 255)] = v;
    }
}

extern "C" void kernel_launch(void* const* d_in, const int* in_sizes, int n_in,
                              void* d_out, int out_size, void* d_ws, size_t ws_size,
                              hipStream_t stream)
{
    const float* x      = (const float*)d_in[0];
    const float* wqkv0  = (const float*)d_in[1];
    const float* wdw0   = (const float*)d_in[2];
    const float* wproj0 = (const float*)d_in[3];
    const float* wqkv1  = (const float*)d_in[4];
    const float* wdw1   = (const float*)d_in[5];
    const float* wproj1 = (const float*)d_in[6];
    float* out = (float*)d_out;

    float* tmp = (float*)d_ws;                       // 33,554,432 floats (134 MB)
    short* fb  = (short*)(tmp + 33554432);
    short* bq0h = fb;                                // 12288 each
    short* bq0l = fb + 12288;
    short* bq1h = fb + 24576;
    short* bq1l = fb + 36864;
    short* bp0h = fb + 49152;                        // 36864 each
    short* bp0l = fb + 86016;
    short* bp1h = fb + 122880;
    short* bp1l = fb + 159744;

    hipLaunchKernelGGL(k_fq, dim3(24), dim3(512), 0, stream, wqkv0, bq0h, bq0l);
    hipLaunchKernelGGL(k_fq, dim3(24), dim3(512), 0, stream, wqkv1, bq1h, bq1l);
    hipLaunchKernelGGL(k_fp, dim3(72), dim3(512), 0, stream, wproj0, bp0h, bp0l);
    hipLaunchKernelGGL(k_fp, dim3(72), dim3(512), 0, stream, wproj1, bp1h, bp1l);

    // pass 1: x -> tmp (no shift/mask/roll)
    hipLaunchKernelGGL(k_fused, dim3(8192), dim3(256), 0, stream,
                       x, bq0h, bq0l, wdw0, bp0h, bp0l, tmp, 0, 0, 0);
    // pass 2: tmp -> out (shift +4 read, Swin mask, roll +4 write)
    hipLaunchKernelGGL(k_fused, dim3(8192), dim3(256), 0, stream,
                       tmp, bq1h, bq1l, wdw1, bp1h, bp1l, out, 4, 1, 4);
}

// Round 8
// 609.960 us; speedup vs baseline: 1.5774x; 1.0154x over previous
//
#include <hip/hip_runtime.h>

// LocalAttention (Swin scrambled-window variant) — all four GEMMs on MFMA.
// Window map (verified pass R2/R3): n=b*1024+c*16+t ; c2=hi*32+lo ; p=r*8+s ;
// h=16t+8hi+r ; w=8lo+s ; mask index = n&1023.
// l2norm folds into k:  attn[i][j] = sum_c q[c][i] * (k[c][j]*0.125/(nq_c*nk_c)).
// Split-bf16 everywhere: x=hi+lo, D += Ah*Bh + Ah*Bl + Al*Bh (rel err ~2^-18).
//
// R8/R9/R10: 32768B arena, 4-5 blocks/CU, spill-free (packed-word SROA fix).
// R11: issue+serialization attack:
//   - Front pipelined: P2(chunk i+1) || DW(chunk i) via A/B double-buffered scr
//     (= K0/K1 bytes). 1 barrier/phase; front 14 -> 9 barriers (total 22 -> 17).
//     Phase mixes MFMA with stencil VALU (separate pipes overlap per wave).
//   - Kernel templated on (SHIFT, MASK, ROLL): pass1 P1/P8 become
//     base + t*4096 + o (no wrap math), mask block compiled out.
//   - kk-addr halving: (kk*32+qo8)^(key<<3) == (qo8^(key<<3))^(kk<<5)
//     (bit-5 disjoint from bits 3-4) -> P2/P5/P7 fragment addrs cost 1 XOR for kk=1.
//   Arena: R1[0,16384) XTin->qT->XTout ; A[16384,24576) B[24576,32768):
//     scr ping-pong -> K0|K1 -> vb|PT -> zero-span+projo.

typedef __attribute__((ext_vector_type(8))) short bf8;
typedef __attribute__((ext_vector_type(4))) float f32x4;
#define MFMA(a, b, c) __builtin_amdgcn_mfma_f32_16x16x32_bf16(a, b, c, 0, 0, 0)

__device__ __forceinline__ int xkey(int p) { return ((p >> 3) ^ p) & 7; }
// bf16 64-wide regions: row p, col c (0..63) -> short index
__device__ __forceinline__ int xswz(int p, int c) { return p * 64 + (c ^ (xkey(p) << 3)); }
// bf16 32-wide regions (kT halves, vb/PT halves): row r, col c (0..31)
__device__ __forceinline__ int kswz(int r, int c) {
    return r * 32 + (c ^ ((((r >> 3) ^ (r >> 1)) & 3) << 3));
}
// scr fp32 (32 ch): stride 64, granule-4 XOR (uniform for P2 store + dw stencil)
__device__ __forceinline__ int sswz(int ch, int p) {
    return ch * 64 + (p ^ (((ch >> 1) & 7) << 2));
}
// projo fp32 (64 ch): stride 64, granule-8 XOR (uniform store, 2-way P8 read)
__device__ __forceinline__ int jswz(int ch, int p) {
    return ch * 64 + (p ^ (((ch >> 1) & 7) << 3));
}

// packed 2xf32 -> 2xbf16 (RNE). No builtin on gfx950 — inline asm (T12/m240).
__device__ __forceinline__ unsigned cvtpk(float a, float b) {
    unsigned r;
    asm("v_cvt_pk_bf16_f32 %0, %1, %2" : "=v"(r) : "v"(a), "v"(b));
    return r;
}

__device__ __forceinline__ void bsplit(float f, short& h, short& l) {
    unsigned u = __float_as_uint(f);
    unsigned hb = (u + 0x7FFFu + ((u >> 16) & 1u)) >> 16;
    float hf = __uint_as_float(hb << 16);
    float r = f - hf;
    unsigned u2 = __float_as_uint(r);
    unsigned lb = (u2 + 0x7FFFu + ((u2 >> 16) & 1u)) >> 16;
    h = (short)hb; l = (short)lb;
}
// a in low half, b in high half. hi = RNE-bf16(x); lo = RNE-bf16(x - hi).
__device__ __forceinline__ void bsplit2(float a, float b, unsigned& hw, unsigned& lw) {
    hw = cvtpk(a, b);
    float ra = a - __uint_as_float(hw << 16);
    float rb = b - __uint_as_float(hw & 0xFFFF0000u);
    lw = cvtpk(ra, rb);
}

// ---- qkv 1x1 weight fragments: [kk(2)][tt(12)][lane(64)][j(8)]  B[n=oc][k=ic] ----
__global__ void k_fq(const float* __restrict__ wq, short* __restrict__ oh, short* __restrict__ ol) {
    int bx = blockIdx.x;                 // kk*12 + tt
    int kk = bx / 12, tt = bx % 12;
    int tid = threadIdx.x;               // 512
    int lane = tid >> 3, j = tid & 7;
    int oc = tt * 16 + (lane & 15);
    int ic = kk * 32 + ((lane >> 4) << 3) + j;
    short h, l; bsplit(wq[oc * 64 + ic], h, l);
    oh[bx * 512 + tid] = h; ol[bx * 512 + tid] = l;
}
// ---- proj 3x3 weight fragments: [tap(9)][kk(2)][tt(4)][lane(64)][j(8)] ----
__global__ void k_fp(const float* __restrict__ wp, short* __restrict__ oh, short* __restrict__ ol) {
    int bx = blockIdx.x;                 // tap*8 + kk*4 + tt
    int tap = bx >> 3, kk = (bx >> 2) & 1, tt = bx & 3;
    int tid = threadIdx.x;
    int lane = tid >> 3, j = tid & 7;
    int oc = tt * 16 + (lane & 15);
    int ic = kk * 32 + ((lane >> 4) << 3) + j;
    short h, l; bsplit(wp[(oc * 64 + ic) * 9 + tap], h, l);
    oh[bx * 512 + tid] = h; ol[bx * 512 + tid] = l;
}

// dw3x3 for ONE channel (local ch 0..31 in scr), one output row, zero pad.
__device__ __forceinline__ void dw_one(const float* scr, const float* wd,
                                       int ch, int row, float o[8]) {
    float w9[9];
    #pragma unroll
    for (int tp = 0; tp < 9; ++tp) w9[tp] = wd[tp];
    float e[3][10];
    #pragma unroll
    for (int k3 = 0; k3 < 3; ++k3) {
        int rr = row - 1 + k3;
        e[k3][0] = 0.f; e[k3][9] = 0.f;
        if ((unsigned)rr < 8u) {
            float4 a = *(const float4*)&scr[sswz(ch, rr * 8)];
            float4 b = *(const float4*)&scr[sswz(ch, rr * 8 + 4)];
            e[k3][1] = a.x; e[k3][2] = a.y; e[k3][3] = a.z; e[k3][4] = a.w;
            e[k3][5] = b.x; e[k3][6] = b.y; e[k3][7] = b.z; e[k3][8] = b.w;
        } else {
            #pragma unroll
            for (int q2 = 1; q2 < 9; ++q2) e[k3][q2] = 0.f;
        }
    }
    #pragma unroll
    for (int s = 0; s < 8; ++s) {
        float a = 0.f;
        #pragma unroll
        for (int k3 = 0; k3 < 3; ++k3)
            #pragma unroll
            for (int dx = 0; dx < 3; ++dx)
                a = fmaf(w9[k3 * 3 + dx], e[k3][s + dx], a);
        o[s] = a;
    }
}

__device__ __forceinline__ float norm8(const float d[8]) {
    float ss = 0.f;
    #pragma unroll
    for (int s = 0; s < 8; ++s) ss = fmaf(d[s], d[s], ss);
    ss += __shfl_xor(ss, 1); ss += __shfl_xor(ss, 2); ss += __shfl_xor(ss, 4);
    return fmaxf(sqrtf(ss), 1e-12f);
}

// P2 chunk: 64px x 32oc x 64ic MFMA 1x1, XTin -> scr.
// chunk selects oc-16-tile pair: 0,1=q ; 2,3=k ; 4,5=v (tt = chunk*2+nh).
__device__ __forceinline__ void p2_chunk32(const short* XTh, const short* XTl,
                                           const short* bqh, const short* bql,
                                           float* scr, int chunk,
                                           int mh, int nh, int col, int quad, int qo8, int lane)
{
    f32x4 acc[2];
    #pragma unroll
    for (int mt = 0; mt < 2; ++mt) acc[mt] = (f32x4){0.f, 0.f, 0.f, 0.f};
    int ad0[2];
    #pragma unroll
    for (int mt = 0; mt < 2; ++mt) {
        int row = (mh * 2 + mt) * 16 + col;
        ad0[mt] = row * 64 + (qo8 ^ (xkey(row) << 3));
    }
    #pragma unroll
    for (int kk = 0; kk < 2; ++kk) {
        bf8 Ah[2], Al[2];
        #pragma unroll
        for (int mt = 0; mt < 2; ++mt) {
            int ad = ad0[mt] ^ (kk << 5);
            Ah[mt] = *(const bf8*)&XTh[ad];
            Al[mt] = *(const bf8*)&XTl[ad];
        }
        int tt = chunk * 2 + nh;
        bf8 Bh = *(const bf8*)&bqh[((kk * 12 + tt) * 64 + lane) * 8];
        bf8 Bl = *(const bf8*)&bql[((kk * 12 + tt) * 64 + lane) * 8];
        #pragma unroll
        for (int mt = 0; mt < 2; ++mt) {
            acc[mt] = MFMA(Ah[mt], Bh, acc[mt]);
            acc[mt] = MFMA(Ah[mt], Bl, acc[mt]);
            acc[mt] = MFMA(Al[mt], Bh, acc[mt]);
        }
    }
    #pragma unroll
    for (int mt = 0; mt < 2; ++mt) {
        int ocl = nh * 16 + col;
        int p0 = (mh * 2 + mt) * 16 + quad * 4;
        *(f32x4*)&scr[sswz(ocl, p0)] = acc[mt];
    }
}

template<int SHIFT, int MASK, int ROLL>
__global__ __launch_bounds__(256, 4)
void k_fused(const float* __restrict__ in,
             const short* __restrict__ bqh, const short* __restrict__ bql,
             const float* __restrict__ wdw,
             const short* __restrict__ bph, const short* __restrict__ bpl,
             float* __restrict__ out)
{
    __shared__ __align__(16) char smem[32768];
    short* XTh = (short*)smem;                 // R1: XTin -> qT -> XTout (8KB)
    short* XTl = (short*)(smem + 8192);        //     (8KB)
    float* bufA = (float*)(smem + 16384);      // front scr ping (8KB)
    float* bufB = (float*)(smem + 24576);      // front scr pong (8KB)
    short* K0h = (short*)(smem + 16384);       // kT c<32 hi (4KB)
    short* K0l = (short*)(smem + 20480);       // kT c<32 lo (4KB)
    short* K1h = (short*)(smem + 24576);       // kT c>=32 hi (4KB)
    short* K1l = (short*)(smem + 28672);       // kT c>=32 lo (4KB)
    short* vbh = (short*)(smem + 16384);       // P6: vb half hi (4KB)
    short* vbl = (short*)(smem + 20480);       //     vb half lo (4KB)
    short* PTf = (short*)(smem + 24576);       //     PT half hi (4KB)
    short* PTg = (short*)(smem + 28672);       //     PT half lo (4KB)
    float* projo = (float*)(smem + 16384);     // after P7 (16KB; zero span at +0)

    const int tid = threadIdx.x, lane = tid & 63, wv = tid >> 6;
    const int col = lane & 15, quad = lane >> 4, qo8 = quad * 8;
    const int mh = wv & 1, nh = wv >> 1;
    const int ch = tid >> 3, rrow = tid & 7;   // DW map: 1 channel/thread
    const int n = blockIdx.x;
    const int b = n >> 10, c = (n >> 4) & 63, t = n & 15;
    const size_t base = ((size_t)(b * 64 + c)) << 16;

    // ---- P1: load window, split via cvt_pk pairs, XTin[p][c2] ----
    // For SHIFT==0: addr = base + t*4096 + o exactly (h2*256+w2 == o).
    #pragma unroll
    for (int k = 0; k < 16; k += 2) {
        int o0 = tid + k * 256, o1 = o0 + 256;
        float v0, v1;
        if (SHIFT == 0) {
            const float* src = in + base + (size_t)t * 4096;
            v0 = src[o0]; v1 = src[o1];
        } else {
            int hi0 = o0 >> 11, r0 = (o0 >> 8) & 7, lo0 = (o0 >> 3) & 31, s0 = o0 & 7;
            int hi1 = o1 >> 11, r1 = (o1 >> 8) & 7, lo1 = (o1 >> 3) & 31, s1 = o1 & 7;
            v0 = in[base + (size_t)(((t * 16 + hi0 * 8 + r0) + SHIFT) & 255) * 256
                         + (((lo0 * 8 + s0) + SHIFT) & 255)];
            v1 = in[base + (size_t)(((t * 16 + hi1 * 8 + r1) + SHIFT) & 255) * 256
                         + (((lo1 * 8 + s1) + SHIFT) & 255)];
        }
        unsigned hw, lw; bsplit2(v0, v1, hw, lw);
        int hi0 = o0 >> 11, r0 = (o0 >> 8) & 7, lo0 = (o0 >> 3) & 31, s0 = o0 & 7;
        int hi1 = o1 >> 11, r1 = (o1 >> 8) & 7, lo1 = (o1 >> 3) & 31, s1 = o1 & 7;
        int ad0 = xswz(r0 * 8 + s0, hi0 * 32 + lo0);
        int ad1 = xswz(r1 * 8 + s1, hi1 * 32 + lo1);
        XTh[ad0] = (short)hw; XTh[ad1] = (short)(hw >> 16);
        XTl[ad0] = (short)lw; XTl[ad1] = (short)(lw >> 16);
    }
    __syncthreads();   // (1)

    // preconverted packed bf16 words (straight-line SROA-safe; rule #20)
    unsigned qAh[4], qAl[4], qBh[4], qBl[4];
    unsigned vAh[4], vAl[4], vBh[4], vBl[4];
    unsigned k0h[4], k0l[4], k1h[4], k1l[4];
    float nqA, nqB;

    // ---- front pipeline: P2(next) || DW(prev), A/B ping-pong, 1 barrier/phase ----
    // ph1: q0 -> A
    p2_chunk32(XTh, XTl, bqh, bql, bufA, 0, mh, nh, col, quad, qo8, lane);
    __syncthreads();   // (2)
    // ph2: q1 -> B || DWq0(A)
    p2_chunk32(XTh, XTl, bqh, bql, bufB, 1, mh, nh, col, quad, qo8, lane);
    {
        float d[8];
        dw_one(bufA, wdw + ch * 9, ch, rrow, d);
        nqA = norm8(d);
        #pragma unroll
        for (int q2 = 0; q2 < 4; ++q2) bsplit2(d[2 * q2], d[2 * q2 + 1], qAh[q2], qAl[q2]);
    }
    __syncthreads();   // (3)
    // ph3: v0 -> A || DWq1(B)
    p2_chunk32(XTh, XTl, bqh, bql, bufA, 4, mh, nh, col, quad, qo8, lane);
    {
        float d[8];
        dw_one(bufB, wdw + (32 + ch) * 9, ch, rrow, d);
        nqB = norm8(d);
        #pragma unroll
        for (int q2 = 0; q2 < 4; ++q2) bsplit2(d[2 * q2], d[2 * q2 + 1], qBh[q2], qBl[q2]);
    }
    __syncthreads();   // (4)
    // ph4: v1 -> B || DWv0(A)
    p2_chunk32(XTh, XTl, bqh, bql, bufB, 5, mh, nh, col, quad, qo8, lane);
    {
        float d[8];
        dw_one(bufA, wdw + (128 + ch) * 9, ch, rrow, d);
        #pragma unroll
        for (int q2 = 0; q2 < 4; ++q2) bsplit2(d[2 * q2], d[2 * q2 + 1], vAh[q2], vAl[q2]);
    }
    __syncthreads();   // (5)
    // ph5: k0 -> A || DWv1(B)
    p2_chunk32(XTh, XTl, bqh, bql, bufA, 2, mh, nh, col, quad, qo8, lane);
    {
        float d[8];
        dw_one(bufB, wdw + (160 + ch) * 9, ch, rrow, d);
        #pragma unroll
        for (int q2 = 0; q2 < 4; ++q2) bsplit2(d[2 * q2], d[2 * q2 + 1], vBh[q2], vBl[q2]);
    }
    __syncthreads();   // (6)
    // ph6: k1 -> B (last XTin reader) || DWk0(A) + scale
    p2_chunk32(XTh, XTl, bqh, bql, bufB, 3, mh, nh, col, quad, qo8, lane);
    {
        float d[8];
        dw_one(bufA, wdw + (64 + ch) * 9, ch, rrow, d);
        float sc = 0.125f / (nqA * norm8(d));
        #pragma unroll
        for (int s = 0; s < 8; ++s) d[s] *= sc;
        #pragma unroll
        for (int q2 = 0; q2 < 4; ++q2) bsplit2(d[2 * q2], d[2 * q2 + 1], k0h[q2], k0l[q2]);
    }
    __syncthreads();   // (7)
    // ph7: DWk1(B) + scale || scatter dk0 -> K0 (=A bytes) || scatter dq -> qT (XT)
    {
        float d[8];
        dw_one(bufB, wdw + (96 + ch) * 9, ch, rrow, d);
        float sc = 0.125f / (nqB * norm8(d));
        #pragma unroll
        for (int s = 0; s < 8; ++s) d[s] *= sc;
        #pragma unroll
        for (int q2 = 0; q2 < 4; ++q2) bsplit2(d[2 * q2], d[2 * q2 + 1], k1h[q2], k1l[q2]);
    }
    #pragma unroll
    for (int q2 = 0; q2 < 4; ++q2) {
        int p0 = rrow * 8 + 2 * q2;
        int a0 = kswz(p0, ch), a1 = kswz(p0 + 1, ch);
        K0h[a0] = (short)k0h[q2]; K0h[a1] = (short)(k0h[q2] >> 16);
        K0l[a0] = (short)k0l[q2]; K0l[a1] = (short)(k0l[q2] >> 16);
        int x0 = xswz(p0, ch), x1 = xswz(p0 + 1, ch);
        XTh[x0] = (short)qAh[q2]; XTh[x1] = (short)(qAh[q2] >> 16);
        XTl[x0] = (short)qAl[q2]; XTl[x1] = (short)(qAl[q2] >> 16);
        int cg = 32 + ch;
        int y0 = xswz(p0, cg), y1 = xswz(p0 + 1, cg);
        XTh[y0] = (short)qBh[q2]; XTh[y1] = (short)(qBh[q2] >> 16);
        XTl[y0] = (short)qBl[q2]; XTl[y1] = (short)(qBl[q2] >> 16);
    }
    __syncthreads();   // (8)
    // ph8: scatter dk1 -> K1 (=B bytes)
    #pragma unroll
    for (int q2 = 0; q2 < 4; ++q2) {
        int p0 = rrow * 8 + 2 * q2;
        int a0 = kswz(p0, ch), a1 = kswz(p0 + 1, ch);
        K1h[a0] = (short)k1h[q2]; K1h[a1] = (short)(k1h[q2] >> 16);
        K1l[a0] = (short)k1l[q2]; K1l[a1] = (short)(k1l[q2] >> 16);
    }
    __syncthreads();   // (9) qT/kT ready

    // ---- P5: MFMA QK^T (M=i rows wv*16.., N=j all 64, K=c) + mask + softmax ----
    f32x4 at[4];
    #pragma unroll
    for (int nt = 0; nt < 4; ++nt) at[nt] = (f32x4){0.f, 0.f, 0.f, 0.f};
    {
        bf8 Ah[2], Al[2];
        int rowA = wv * 16 + col;
        int adA0 = rowA * 64 + (qo8 ^ (xkey(rowA) << 3));
        #pragma unroll
        for (int kk = 0; kk < 2; ++kk) {
            int ad = adA0 ^ (kk << 5);
            Ah[kk] = *(const bf8*)&XTh[ad];   // qT
            Al[kk] = *(const bf8*)&XTl[ad];
        }
        #pragma unroll
        for (int kk = 0; kk < 2; ++kk) {
            const short* Bph = kk ? K1h : K0h;
            const short* Bpl = kk ? K1l : K0l;
            #pragma unroll
            for (int nt = 0; nt < 4; ++nt) {
                int rowB = nt * 16 + col;
                int ad = kswz(rowB, qo8);
                bf8 Bh = *(const bf8*)&Bph[ad];
                bf8 Bl = *(const bf8*)&Bpl[ad];
                at[nt] = MFMA(Ah[kk], Bh, at[nt]);
                at[nt] = MFMA(Ah[kk], Bl, at[nt]);
                at[nt] = MFMA(Al[kk], Bh, at[nt]);
            }
        }
    }
    if (MASK) {
        const int widx = n & 1023;
        const int hn_m = widx >> 5, wn_m = widx & 31;
        #pragma unroll
        for (int nt = 0; nt < 4; ++nt) {
            int j = nt * 16 + col;
            int rj = ((hn_m == 31) ? (((j >> 3) < 4) ? 1 : 2) : 0) * 3
                   + ((wn_m == 31) ? (((j & 7) < 4) ? 1 : 2) : 0);
            #pragma unroll
            for (int rg = 0; rg < 4; ++rg) {
                int i = wv * 16 + quad * 4 + rg;
                int ri = ((hn_m == 31) ? (((i >> 3) < 4) ? 1 : 2) : 0) * 3
                       + ((wn_m == 31) ? (((i & 7) < 4) ? 1 : 2) : 0);
                if (ri != rj) at[nt][rg] = at[nt][rg] - 100.f;
            }
        }
    }
    unsigned Ph[4][2], Pl[4][2];
    {
        float Pv[4][4];
        #pragma unroll
        for (int rg = 0; rg < 4; ++rg) {
            float m = fmaxf(fmaxf(at[0][rg], at[1][rg]), fmaxf(at[2][rg], at[3][rg]));
            m = fmaxf(m, __shfl_xor(m, 1)); m = fmaxf(m, __shfl_xor(m, 2));
            m = fmaxf(m, __shfl_xor(m, 4)); m = fmaxf(m, __shfl_xor(m, 8));
            float e0 = __expf(at[0][rg] - m), e1 = __expf(at[1][rg] - m);
            float e2 = __expf(at[2][rg] - m), e3 = __expf(at[3][rg] - m);
            float s = e0 + e1 + e2 + e3;
            s += __shfl_xor(s, 1); s += __shfl_xor(s, 2);
            s += __shfl_xor(s, 4); s += __shfl_xor(s, 8);
            float is = 1.0f / s;
            Pv[0][rg] = e0 * is; Pv[1][rg] = e1 * is; Pv[2][rg] = e2 * is; Pv[3][rg] = e3 * is;
        }
        // preconvert straight-line (divergent PT-write uses only these words)
        #pragma unroll
        for (int nt = 0; nt < 4; ++nt)
            #pragma unroll
            for (int rp = 0; rp < 2; ++rp)
                bsplit2(Pv[nt][2 * rp], Pv[nt][2 * rp + 1], Ph[nt][rp], Pl[nt][rp]);
    }
    __syncthreads();   // (10) qT/kT reads done

    // ---- P6: M=c, N=j, K=i in two i-halves; acc in regs across halves. ----
    f32x4 av[2][2];
    #pragma unroll
    for (int mt = 0; mt < 2; ++mt)
        #pragma unroll
        for (int nt = 0; nt < 2; ++nt) av[mt][nt] = (f32x4){0.f, 0.f, 0.f, 0.f};
    #pragma unroll
    for (int ih = 0; ih < 2; ++ih) {
        // write vb half: threads whose rrow-half matches (i = rrow*8+s)
        if ((rrow >> 2) == ih) {
            int rl = rrow & 3;
            int adA = kswz(ch, rl * 8);
            *(uint4*)&vbh[adA] = (uint4){vAh[0], vAh[1], vAh[2], vAh[3]};
            *(uint4*)&vbl[adA] = (uint4){vAl[0], vAl[1], vAl[2], vAl[3]};
            int adB = kswz(32 + ch, rl * 8);
            *(uint4*)&vbh[adB] = (uint4){vBh[0], vBh[1], vBh[2], vBh[3]};
            *(uint4*)&vbl[adB] = (uint4){vBl[0], vBl[1], vBl[2], vBl[3]};
        }
        // write PT half: waves whose i-range matches (i = wv*16+quad*4+rg)
        if ((wv >> 1) == ih) {
            #pragma unroll
            for (int nt = 0; nt < 4; ++nt) {
                int j = nt * 16 + col;
                #pragma unroll
                for (int rp = 0; rp < 2; ++rp) {
                    int il = (wv & 1) * 16 + quad * 4 + 2 * rp;
                    int ad = kswz(j, il);
                    *(unsigned*)&PTf[ad] = Ph[nt][rp];
                    *(unsigned*)&PTg[ad] = Pl[nt][rp];
                }
            }
        }
        __syncthreads();   // (11)/(13)
        {
            bf8 Ah[2], Al[2], Bh[2], Bl[2];
            #pragma unroll
            for (int mt = 0; mt < 2; ++mt) {
                int row = (mh * 2 + mt) * 16 + col;
                int ad = kswz(row, qo8);
                Ah[mt] = *(const bf8*)&vbh[ad];
                Al[mt] = *(const bf8*)&vbl[ad];
            }
            #pragma unroll
            for (int nt = 0; nt < 2; ++nt) {
                int rowB = (nh * 2 + nt) * 16 + col;
                int ad = kswz(rowB, qo8);
                Bh[nt] = *(const bf8*)&PTf[ad];
                Bl[nt] = *(const bf8*)&PTg[ad];
            }
            #pragma unroll
            for (int mt = 0; mt < 2; ++mt)
                #pragma unroll
                for (int nt = 0; nt < 2; ++nt) {
                    av[mt][nt] = MFMA(Ah[mt], Bh[nt], av[mt][nt]);
                    av[mt][nt] = MFMA(Ah[mt], Bl[nt], av[mt][nt]);
                    av[mt][nt] = MFMA(Al[mt], Bh[nt], av[mt][nt]);
                }
        }
        __syncthreads();   // (12)/(14) half reads done
    }
    // XTout writes (qT dead; visible to P7 after barrier (15))
    #pragma unroll
    for (int nt = 0; nt < 2; ++nt) {
        int j = (nh * 2 + nt) * 16 + col;
        #pragma unroll
        for (int mt = 0; mt < 2; ++mt) {
            int c0 = (mh * 2 + mt) * 16 + quad * 4;
            #pragma unroll
            for (int rp = 0; rp < 2; ++rp) {
                unsigned hw, lw; bsplit2(av[mt][nt][2 * rp], av[mt][nt][2 * rp + 1], hw, lw);
                int ad = j * 64 + ((c0 + 2 * rp) ^ (xkey(j) << 3));
                *(unsigned*)&XTh[ad] = hw;
                *(unsigned*)&XTl[ad] = lw;
            }
        }
    }
    // zero span for P7 OOB reads: smem[16384,16512) (vb/PT dead after (14))
    if (tid < 32) ((unsigned*)(smem + 16384))[tid] = 0u;
    __syncthreads();   // (15)

    // ---- P7: MFMA proj conv = 9 shifted GEMMs. M=p, N=oc, K=ic. OOB -> zero span
    //      via magic rows: 128 (XTh base) / 64 (XTl base) -> byte 16384, xkey=0. ----
    {
        f32x4 ap[2][2];
        #pragma unroll
        for (int mt = 0; mt < 2; ++mt)
            #pragma unroll
            for (int nt = 0; nt < 2; ++nt) ap[mt][nt] = (f32x4){0.f, 0.f, 0.f, 0.f};
        const int smc = col & 7;
        #pragma unroll 1
        for (int tap = 0; tap < 9; ++tap) {
            int dy = (tap >= 6) ? 1 : ((tap >= 3) ? 0 : -1);
            int dx = tap - (dy + 1) * 3 - 1;
            int bh0[2], bl0[2];
            #pragma unroll
            for (int mt = 0; mt < 2; ++mt) {
                int rr = (mh * 2 + mt) * 2 + (col >> 3) + dy;
                int ss = smc + dx;
                bool ok = ((unsigned)rr < 8u) && ((unsigned)ss < 8u);
                int row = rr * 8 + ss;
                int ra_h = ok ? row : 128;
                int ra_l = ok ? row : 64;
                bh0[mt] = ra_h * 64 + (qo8 ^ (xkey(ra_h) << 3));
                bl0[mt] = ra_l * 64 + (qo8 ^ (xkey(ra_l) << 3));
            }
            #pragma unroll
            for (int kk = 0; kk < 2; ++kk) {
                bf8 Bh[2], Bl[2], Ah[2], Al[2];
                #pragma unroll
                for (int nt = 0; nt < 2; ++nt) {
                    int bi = (((tap * 2 + kk) * 4 + (nh * 2 + nt)) * 64 + lane) * 8;
                    Bh[nt] = *(const bf8*)&bph[bi];
                    Bl[nt] = *(const bf8*)&bpl[bi];
                }
                #pragma unroll
                for (int mt = 0; mt < 2; ++mt) {
                    Ah[mt] = *(const bf8*)&XTh[bh0[mt] ^ (kk << 5)];
                    Al[mt] = *(const bf8*)&XTl[bl0[mt] ^ (kk << 5)];
                }
                #pragma unroll
                for (int mt = 0; mt < 2; ++mt)
                    #pragma unroll
                    for (int nt = 0; nt < 2; ++nt) {
                        ap[mt][nt] = MFMA(Ah[mt], Bh[nt], ap[mt][nt]);
                        ap[mt][nt] = MFMA(Ah[mt], Bl[nt], ap[mt][nt]);
                        ap[mt][nt] = MFMA(Al[mt], Bh[nt], ap[mt][nt]);
                    }
            }
        }
        __syncthreads();   // (16) all tap reads (incl. zero span) done
        #pragma unroll
        for (int nt = 0; nt < 2; ++nt) {
            int oc = (nh * 2 + nt) * 16 + col;
            #pragma unroll
            for (int mt = 0; mt < 2; ++mt) {
                int p0 = (mh * 2 + mt) * 16 + quad * 4;
                *(f32x4*)&projo[jswz(oc, p0)] = ap[mt][nt];
            }
        }
    }
    __syncthreads();   // (17)

    // ---- P8: window reverse + roll, coalesced image-order stores ----
    #pragma unroll
    for (int k = 0; k < 16; ++k) {
        int o = tid + k * 256;
        int hi = o >> 11, r = (o >> 8) & 7, lo = (o >> 3) & 31, s = o & 7;
        int c2 = hi * 32 + lo;
        float v = projo[jswz(c2, r * 8 + s)];
        if (ROLL == 0) {
            float* dst = out + base + (size_t)t * 4096;
            dst[o] = v;
        } else {
            int h2 = t * 16 + hi * 8 + r, w2 = lo * 8 + s;
            out[base + (size_t)((h2 + ROLL) & 255) * 256 + ((w2 + ROLL) & 255)] = v;
        }
    }
}

extern "C" void kernel_launch(void* const* d_in, const int* in_sizes, int n_in,
                              void* d_out, int out_size, void* d_ws, size_t ws_size,
                              hipStream_t stream)
{
    const float* x      = (const float*)d_in[0];
    const float* wqkv0  = (const float*)d_in[1];
    const float* wdw0   = (const float*)d_in[2];
    const float* wproj0 = (const float*)d_in[3];
    const float* wqkv1  = (const float*)d_in[4];
    const float* wdw1   = (const float*)d_in[5];
    const float* wproj1 = (const float*)d_in[6];
    float* out = (float*)d_out;

    float* tmp = (float*)d_ws;                       // 33,554,432 floats (134 MB)
    short* fb  = (short*)(tmp + 33554432);
    short* bq0h = fb;                                // 12288 each
    short* bq0l = fb + 12288;
    short* bq1h = fb + 24576;
    short* bq1l = fb + 36864;
    short* bp0h = fb + 49152;                        // 36864 each
    short* bp0l = fb + 86016;
    short* bp1h = fb + 122880;
    short* bp1l = fb + 159744;

    hipLaunchKernelGGL(k_fq, dim3(24), dim3(512), 0, stream, wqkv0, bq0h, bq0l);
    hipLaunchKernelGGL(k_fq, dim3(24), dim3(512), 0, stream, wqkv1, bq1h, bq1l);
    hipLaunchKernelGGL(k_fp, dim3(72), dim3(512), 0, stream, wproj0, bp0h, bp0l);
    hipLaunchKernelGGL(k_fp, dim3(72), dim3(512), 0, stream, wproj1, bp1h, bp1l);

    // pass 1: x -> tmp (no shift/mask/roll; specialized instantiation)
    hipLaunchKernelGGL(HIP_KERNEL_NAME(k_fused<0, 0, 0>), dim3(8192), dim3(256), 0, stream,
                       x, bq0h, bq0l, wdw0, bp0h, bp0l, tmp);
    // pass 2: tmp -> out (shift +4 read, Swin mask, roll +4 write)
    hipLaunchKernelGGL(HIP_KERNEL_NAME(k_fused<4, 1, 4>), dim3(8192), dim3(256), 0, stream,
                       tmp, bq1h, bq1l, wdw1, bp1h, bp1l, out);
}